// Round 8
// baseline (151.695 us; speedup 1.0000x reference)
//
#include <hip/hip_runtime.h>
#include <hip/hip_bf16.h>

typedef __hip_bfloat16 bf16;
typedef __attribute__((ext_vector_type(8))) short short8;
typedef __attribute__((ext_vector_type(4))) float f32x4;

#define SL 1024
#define DIM 512
#define NH 8
#define HD 64
#define NBUCK 128

__device__ __forceinline__ float silu_f(float x) { return x / (1.0f + __expf(-x)); }

__device__ __forceinline__ short f2bf(float x) {
  bf16 b = __float2bfloat16(x);
  return *reinterpret_cast<short*>(&b);
}

__device__ __forceinline__ void gld_lds16(const void* g, void* l) {
  __builtin_amdgcn_global_load_lds(
      (const __attribute__((address_space(1))) void*)g,
      (__attribute__((address_space(3))) void*)l, 16, 0, 0);
}

// swizzled LDS offsets (in shorts); chunk = 8 shorts = 16B
__device__ __forceinline__ int sw64(int row, int chunk) {   // [_][64] tiles
  return row * 64 + (((chunk ^ row) & 7) << 3) + ((chunk & ~7) << 3);
}
__device__ __forceinline__ int sw128(int row, int chunk) {  // [_][128] tiles
  return row * 128 + (((chunk ^ row) & 7) << 3) + ((chunk & ~7) << 3);
}

// ---------- weight f32 -> bf16 ----------
__global__ void convert_w_k(const float* __restrict__ s0, const float* __restrict__ s1,
                            const float* __restrict__ s2, const float* __restrict__ s3,
                            const float* __restrict__ s4, bf16* __restrict__ dst) {
  int wsel = blockIdx.y;
  const float* src = wsel == 0 ? s0 : wsel == 1 ? s1 : wsel == 2 ? s2 : wsel == 3 ? s3 : s4;
  int i = (blockIdx.x * 256 + threadIdx.x) * 4;
  float4 v = *(const float4*)(src + i);
  bf16* d = dst + (size_t)wsel * DIM * DIM + i;
  d[0] = __float2bfloat16(v.x);
  d[1] = __float2bfloat16(v.y);
  d[2] = __float2bfloat16(v.z);
  d[3] = __float2bfloat16(v.w);
}

// ---------- rmsnorm(hidden) -> bf16 h ----------
__global__ void rmsnorm_k(const float* __restrict__ x, const float* __restrict__ w,
                          bf16* __restrict__ out) {
  int row = blockIdx.x, l = threadIdx.x;  // 64 threads
  const float4* xr = (const float4*)(x + (size_t)row * DIM);
  float4 v0 = xr[l], v1 = xr[l + 64];
  float s = v0.x*v0.x + v0.y*v0.y + v0.z*v0.z + v0.w*v0.w
          + v1.x*v1.x + v1.y*v1.y + v1.z*v1.z + v1.w*v1.w;
  #pragma unroll
  for (int o = 32; o; o >>= 1) s += __shfl_xor(s, o);
  float sc = rsqrtf(s * (1.0f / DIM) + 1e-6f);
  bf16* orow = out + (size_t)row * DIM;
  int c0 = l * 4, c1 = 256 + l * 4;
  orow[c0 + 0] = __float2bfloat16(v0.x * sc * w[c0 + 0]);
  orow[c0 + 1] = __float2bfloat16(v0.y * sc * w[c0 + 1]);
  orow[c0 + 2] = __float2bfloat16(v0.z * sc * w[c0 + 2]);
  orow[c0 + 3] = __float2bfloat16(v0.w * sc * w[c0 + 3]);
  orow[c1 + 0] = __float2bfloat16(v1.x * sc * w[c1 + 0]);
  orow[c1 + 1] = __float2bfloat16(v1.y * sc * w[c1 + 1]);
  orow[c1 + 2] = __float2bfloat16(v1.z * sc * w[c1 + 2]);
  orow[c1 + 3] = __float2bfloat16(v1.w * sc * w[c1 + 3]);
}

// ---------- shared 128x128 GEMM core: C = A(Mx512) * Bt(Nx512)^T ----------
__device__ __forceinline__ void gemm128_core(const bf16* __restrict__ A,
                                             const bf16* __restrict__ Bt,
                                             short* lds, int bm, int bn,
                                             f32x4 acc[4][4]) {
  int t = threadIdx.x, w = t >> 6, l = t & 63;
  int ln = l & 15, g8 = (l >> 4) * 8;
  int wr = (w >> 1) * 64, wc = (w & 1) * 64;
  for (int kt = 0; kt < 16; ++kt) {
    if (kt) __syncthreads();
    #pragma unroll
    for (int i = 0; i < 4; ++i) {
      int s = i * 4 + w;                 // 0..15; 0-7 = A tile, 8-15 = B tile
      int row = s * 16 + (l >> 2);       // within 0..255
      int col = kt * 32 + (l & 3) * 8;
      const bf16* gsrc = (s < 8)
          ? (A  + (size_t)(bm * 128 + row) * DIM + col)
          : (Bt + (size_t)(bn * 128 + row - 128) * DIM + col);
      gld_lds16(gsrc, lds + s * 512 + l * 8);
    }
    __syncthreads();
    short8 a[4], b[4];
    #pragma unroll
    for (int m = 0; m < 4; ++m)
      a[m] = *(const short8*)(lds + (wr + m * 16 + ln) * 32 + g8);
    #pragma unroll
    for (int n = 0; n < 4; ++n)
      b[n] = *(const short8*)(lds + 4096 + (wc + n * 16 + ln) * 32 + g8);
    #pragma unroll
    for (int m = 0; m < 4; ++m)
      #pragma unroll
      for (int n = 0; n < 4; ++n)
        acc[m][n] = __builtin_amdgcn_mfma_f32_16x16x32_bf16(a[m], b[n], acc[m][n], 0, 0, 0);
  }
}

// ---------- q,k,v,u = silu(h @ W^T); q/k/v in [b,h,l,d], u row-major ----------
__global__ __launch_bounds__(256) void gemm_qkvu_k(const bf16* __restrict__ hb,
                                                   const bf16* __restrict__ wb,
                                                   bf16* __restrict__ q, bf16* __restrict__ k,
                                                   bf16* __restrict__ v, bf16* __restrict__ u) {
  __shared__ __align__(16) short lds[8192];
  int mode = blockIdx.y;
  int bm = blockIdx.x >> 2, bn = blockIdx.x & 3;
  f32x4 acc[4][4];
  #pragma unroll
  for (int m = 0; m < 4; ++m)
    #pragma unroll
    for (int n = 0; n < 4; ++n) { f32x4 z = {0.f, 0.f, 0.f, 0.f}; acc[m][n] = z; }
  gemm128_core(hb, wb + (size_t)mode * DIM * DIM, lds, bm, bn, acc);

  int t = threadIdx.x, w = t >> 6, l = t & 63;
  int ln = l & 15, l4 = (l >> 4) * 4;
  int wr = (w >> 1) * 64, wc = (w & 1) * 64;
  bf16* qkv = mode == 0 ? q : mode == 1 ? k : v;
  #pragma unroll
  for (int m = 0; m < 4; ++m)
    #pragma unroll
    for (int n = 0; n < 4; ++n)
      #pragma unroll
      for (int j = 0; j < 4; ++j) {
        int rg = bm * 128 + wr + m * 16 + l4 + j;
        int cg = bn * 128 + wc + n * 16 + ln;
        bf16 val = __float2bfloat16(silu_f(acc[m][n][j]));
        int b = rg >> 10, li = rg & 1023, hh = cg >> 6, dd = cg & 63;
        if (mode <= 2) qkv[((size_t)(b * NH + hh) * SL + li) * HD + dd] = val;
        else           u[(size_t)rg * DIM + cg] = val;
      }
}

// ---------- vT[b,h,d,l] = transpose(v[b,h,l,d]) ----------
__global__ __launch_bounds__(256) void transpose_v_k(const bf16* __restrict__ v,
                                                     bf16* __restrict__ vT) {
  int bh = blockIdx.y, t0 = blockIdx.x * 64;
  int t = threadIdx.x;
  __shared__ short ldsT[64 * 65];
  const bf16* vb = v + (size_t)bh * SL * HD;
  bf16* vtb = vT + (size_t)bh * HD * SL;
  int r = t >> 2, c = (t & 3) * 16;
  short8 x0 = *(const short8*)(vb + (size_t)(t0 + r) * HD + c);
  short8 x1 = *(const short8*)(vb + (size_t)(t0 + r) * HD + c + 8);
  #pragma unroll
  for (int qq = 0; qq < 8; ++qq) {
    ldsT[r * 65 + c + qq] = x0[qq];
    ldsT[r * 65 + c + 8 + qq] = x1[qq];
  }
  __syncthreads();
  int d = t >> 2, lc = (t & 3) * 16;
  short8 y0, y1;
  #pragma unroll
  for (int qq = 0; qq < 8; ++qq) {
    y0[qq] = ldsT[(lc + qq) * 65 + d];
    y1[qq] = ldsT[(lc + 8 + qq) * 65 + d];
  }
  bf16* dst = vtb + (size_t)d * SL + t0 + lc;
  *(short8*)dst = y0;
  *(short8*)(dst + 8) = y1;
}

// ---------- fused: S = silu(qk^T+bias)/L -> attn (f32) ; ao_partial = S @ V ----------
__global__ __launch_bounds__(256) void attn_fused_k(
    const bf16* __restrict__ q, const bf16* __restrict__ k,
    const bf16* __restrict__ vT, const int* __restrict__ ts,
    const float* __restrict__ ts_w, const float* __restrict__ pos_w,
    float* __restrict__ attn, float* __restrict__ ao0, float* __restrict__ ao1) {
  int bm = blockIdx.x, bh = blockIdx.y, z = blockIdx.z;
  int t = threadIdx.x, w = t >> 6, l = t & 63;
  int ln = l & 15, l4 = (l >> 4) * 4, g8 = (l >> 4) * 8;
  int wr = (w >> 1) * 64, wc = (w & 1) * 64;

  __shared__ __align__(16) short Kl[8192];   // [128][64] swizzled
  __shared__ __align__(16) short Vl[8192];   // [64][128] swizzled
  __shared__ __align__(16) short Sl[16384];  // [128][128] swizzled
  __shared__ float tw_l[NBUCK + 1];
  __shared__ float pw_l[255];
  __shared__ int tsi_l[128], tsj_l[128];

  float* arow = attn + (size_t)bh * SL * SL;
  const bf16* qg = q + (size_t)bh * SL * HD;
  const bf16* kg = k + (size_t)bh * SL * HD;
  const bf16* vg = vT + (size_t)bh * HD * SL;
  const int* tsb = ts + (size_t)(bh >> 3) * SL;

  // folded zero-fill of strict-upper tiles: block f handles tiles 2f, 2f+1
  int f = bm * 2 + z;
  #pragma unroll
  for (int zt = 0; zt < 2; ++zt) {
    int idx = f * 2 + zt;
    if (idx < 28) {
      int zi = 0, a2 = 0;
      while (a2 + (7 - zi) <= idx) { a2 += 7 - zi; ++zi; }
      int zj = zi + 1 + (idx - a2);
      float4 z4 = make_float4(0.f, 0.f, 0.f, 0.f);
      #pragma unroll
      for (int rep = 0; rep < 16; ++rep) {
        int flat = rep * 256 + t;
        int row = flat >> 5, c4 = flat & 31;
        *(float4*)(arow + (size_t)(zi * 128 + row) * SL + zj * 128 + c4 * 4) = z4;
      }
    }
  }

  // per-block tables
  if (t < NBUCK + 1) tw_l[t] = ts_w[t];
  if (t >= 128) tsi_l[t - 128] = tsb[min(bm * 128 + (t - 128) + 1, SL - 1)];

  int n0 = (bm + 2) >> 1;
  int lo = z ? n0 : 0;
  int hi = z ? (bm + 1) : n0;

  short8 qa[4][2];
  if (lo < hi) {
    #pragma unroll
    for (int m = 0; m < 4; ++m)
      #pragma unroll
      for (int kb = 0; kb < 2; ++kb)
        qa[m][kb] = *(const short8*)(qg + (size_t)(bm * 128 + wr + m * 16 + ln) * HD + kb * 32 + g8);
    // stage K/V for kt = lo (pre-swizzled global source, linear LDS dest)
    #pragma unroll
    for (int i = 0; i < 4; ++i) {
      int s = i * 4 + w;
      int rk = s * 8 + (l >> 3), ck = (l & 7) ^ (rk & 7);
      gld_lds16(kg + (size_t)(lo * 128 + rk) * HD + ck * 8, Kl + s * 512 + l * 8);
      int rv = s * 4 + (l >> 4), cv = (l & 15) ^ (rv & 7);
      gld_lds16(vg + (size_t)rv * SL + lo * 128 + cv * 8, Vl + s * 512 + l * 8);
    }
    // per-kt tables for kt = lo
    if (t < 128) {
      tsj_l[t] = tsb[lo * 128 + t];
      if (t < 127) pw_l[128 + t] = pos_w[896 + (lo - bm) * 128 + 128 + t];
    } else {
      pw_l[t - 128] = pos_w[896 + (lo - bm) * 128 + (t - 128)];
    }
  }
  __syncthreads();

  f32x4 apv[2][4];
  #pragma unroll
  for (int m = 0; m < 2; ++m)
    #pragma unroll
    for (int n = 0; n < 4; ++n) { f32x4 zz = {0.f, 0.f, 0.f, 0.f}; apv[m][n] = zz; }

  const float LSC = 2.30281455f;       // ln2 / 0.301
  for (int kt = lo; kt < hi; ++kt) {
    // ---- QK ----
    f32x4 acc[4][4];
    #pragma unroll
    for (int m = 0; m < 4; ++m)
      #pragma unroll
      for (int n = 0; n < 4; ++n) { f32x4 zz = {0.f, 0.f, 0.f, 0.f}; acc[m][n] = zz; }
    #pragma unroll
    for (int kb = 0; kb < 2; ++kb) {
      short8 b[4];
      #pragma unroll
      for (int n = 0; n < 4; ++n)
        b[n] = *(const short8*)(Kl + sw64(wc + n * 16 + ln, kb * 4 + (l >> 4)));
      #pragma unroll
      for (int m = 0; m < 4; ++m)
        #pragma unroll
        for (int n = 0; n < 4; ++n)
          acc[m][n] = __builtin_amdgcn_mfma_f32_16x16x32_bf16(qa[m][kb], b[n], acc[m][n], 0, 0, 0);
    }
    // ---- bias + silu epilogue: write attn f32 + Sl bf16 ----
    #pragma unroll
    for (int m = 0; m < 4; ++m)
      #pragma unroll
      for (int j = 0; j < 4; ++j) {
        int il = wr + m * 16 + l4 + j;
        int i = bm * 128 + il;
        int tsi = tsi_l[il];
        #pragma unroll
        for (int n = 0; n < 4; ++n) {
          int jl = wc + n * 16 + ln;
          int jj = kt * 128 + jl;
          float v = acc[m][n][j];
          int dt = tsi - tsj_l[jl];
          float adf = fmaxf(fabsf((float)dt), 1.0f);
          int bucket = (int)(__log2f(adf) * LSC);
          bucket = bucket < 0 ? 0 : (bucket > NBUCK ? NBUCK : bucket);
          float bias = tw_l[bucket] + pw_l[jl - il + 127];
          float o = (jj <= i) ? silu_f(v + bias) * (1.0f / (float)SL) : 0.0f;
          arow[(size_t)i * SL + jj] = o;
          Sl[sw128(il, jl >> 3) + (jl & 7)] = f2bf(o);
        }
      }
    __syncthreads();  // Sl ready
    // ---- PV: apv += Sl @ Vl ----
    #pragma unroll
    for (int kb = 0; kb < 4; ++kb) {
      short8 a2[2], b2[4];
      #pragma unroll
      for (int m = 0; m < 2; ++m)
        a2[m] = *(const short8*)(Sl + sw128(w * 32 + m * 16 + ln, kb * 4 + (l >> 4)));
      #pragma unroll
      for (int n = 0; n < 4; ++n)
        b2[n] = *(const short8*)(Vl + sw128(n * 16 + ln, kb * 4 + (l >> 4)));
      #pragma unroll
      for (int m = 0; m < 2; ++m)
        #pragma unroll
        for (int n = 0; n < 4; ++n)
          apv[m][n] = __builtin_amdgcn_mfma_f32_16x16x32_bf16(a2[m], b2[n], apv[m][n], 0, 0, 0);
    }
    if (kt + 1 < hi) {
      __syncthreads();  // Kl/Vl/Sl free
      int nk = kt + 1;
      #pragma unroll
      for (int i = 0; i < 4; ++i) {
        int s = i * 4 + w;
        int rk = s * 8 + (l >> 3), ck = (l & 7) ^ (rk & 7);
        gld_lds16(kg + (size_t)(nk * 128 + rk) * HD + ck * 8, Kl + s * 512 + l * 8);
        int rv = s * 4 + (l >> 4), cv = (l & 15) ^ (rv & 7);
        gld_lds16(vg + (size_t)rv * SL + nk * 128 + cv * 8, Vl + s * 512 + l * 8);
      }
      if (t < 128) {
        tsj_l[t] = tsb[nk * 128 + t];
        if (t < 127) pw_l[128 + t] = pos_w[896 + (nk - bm) * 128 + 128 + t];
      } else {
        pw_l[t - 128] = pos_w[896 + (nk - bm) * 128 + (t - 128)];
      }
      __syncthreads();  // staged data visible
    }
  }

  float* aop = z ? ao1 : ao0;
  int b = bh >> 3, hh = bh & 7;
  #pragma unroll
  for (int m = 0; m < 2; ++m)
    #pragma unroll
    for (int n = 0; n < 4; ++n)
      #pragma unroll
      for (int j = 0; j < 4; ++j) {
        int i = bm * 128 + w * 32 + m * 16 + l4 + j;
        int dd = n * 16 + ln;
        aop[((size_t)(b * SL + i)) * DIM + hh * HD + dd] = apv[m][n][j];
      }
}

// ---------- gated = u * rmsnorm(ao0+ao1) * attn_ln_w ----------
__global__ void gated_k(const float* __restrict__ ao0, const float* __restrict__ ao1,
                        const bf16* __restrict__ u,
                        const float* __restrict__ w, bf16* __restrict__ g) {
  int row = blockIdx.x, l = threadIdx.x;  // 64 threads
  const float4* ar0 = (const float4*)(ao0 + (size_t)row * DIM);
  const float4* ar1 = (const float4*)(ao1 + (size_t)row * DIM);
  float4 p0 = ar0[l], p1 = ar1[l], p2 = ar0[l + 64], p3 = ar1[l + 64];
  float4 a0 = make_float4(p0.x + p1.x, p0.y + p1.y, p0.z + p1.z, p0.w + p1.w);
  float4 a1 = make_float4(p2.x + p3.x, p2.y + p3.y, p2.z + p3.z, p2.w + p3.w);
  float s = a0.x*a0.x + a0.y*a0.y + a0.z*a0.z + a0.w*a0.w
          + a1.x*a1.x + a1.y*a1.y + a1.z*a1.z + a1.w*a1.w;
  #pragma unroll
  for (int o = 32; o; o >>= 1) s += __shfl_xor(s, o);
  float sc = rsqrtf(s * (1.0f / DIM) + 1e-6f);
  const bf16* ur = u + (size_t)row * DIM;
  bf16* gr = g + (size_t)row * DIM;
  int c0 = l * 4, c1 = 256 + l * 4;
  gr[c0 + 0] = __float2bfloat16(__bfloat162float(ur[c0 + 0]) * a0.x * sc * w[c0 + 0]);
  gr[c0 + 1] = __float2bfloat16(__bfloat162float(ur[c0 + 1]) * a0.y * sc * w[c0 + 1]);
  gr[c0 + 2] = __float2bfloat16(__bfloat162float(ur[c0 + 2]) * a0.z * sc * w[c0 + 2]);
  gr[c0 + 3] = __float2bfloat16(__bfloat162float(ur[c0 + 3]) * a0.w * sc * w[c0 + 3]);
  gr[c1 + 0] = __float2bfloat16(__bfloat162float(ur[c1 + 0]) * a1.x * sc * w[c1 + 0]);
  gr[c1 + 1] = __float2bfloat16(__bfloat162float(ur[c1 + 1]) * a1.y * sc * w[c1 + 1]);
  gr[c1 + 2] = __float2bfloat16(__bfloat162float(ur[c1 + 2]) * a1.z * sc * w[c1 + 2]);
  gr[c1 + 3] = __float2bfloat16(__bfloat162float(ur[c1 + 3]) * a1.w * sc * w[c1 + 3]);
}

// ---------- out = residual + gated @ wo^T, 128x64 tiles, 256 blocks ----------
__global__ __launch_bounds__(256) void gemm_out_k(const bf16* __restrict__ gated,
                                                  const bf16* __restrict__ wob,
                                                  const float* __restrict__ residual,
                                                  float* __restrict__ out) {
  int bm = blockIdx.x >> 3, bn = blockIdx.x & 7;
  int t = threadIdx.x, w = t >> 6, l = t & 63;
  int ln = l & 15, l4 = (l >> 4) * 4, g8 = (l >> 4) * 8;
  __shared__ __align__(16) short lds[6144];  // A tile [128][32], B tile [64][32]
  f32x4 acc[2][4];
  #pragma unroll
  for (int m = 0; m < 2; ++m)
    #pragma unroll
    for (int n = 0; n < 4; ++n) { f32x4 z = {0.f, 0.f, 0.f, 0.f}; acc[m][n] = z; }

  for (int kt = 0; kt < 16; ++kt) {
    if (kt) __syncthreads();
    #pragma unroll
    for (int i = 0; i < 3; ++i) {
      int s = i * 4 + w;               // 0..11; 0-7 A, 8-11 B
      int col = kt * 32 + (l & 3) * 8;
      const bf16* g;
      if (s < 8) { int row = s * 16 + (l >> 2); g = gated + (size_t)(bm * 128 + row) * DIM + col; }
      else       { int r2 = (s - 8) * 16 + (l >> 2); g = wob + (size_t)(bn * 64 + r2) * DIM + col; }
      gld_lds16(g, lds + s * 512 + l * 8);
    }
    __syncthreads();
    short8 a[2], b[4];
    #pragma unroll
    for (int m = 0; m < 2; ++m)
      a[m] = *(const short8*)(lds + (w * 32 + m * 16 + ln) * 32 + g8);
    #pragma unroll
    for (int n = 0; n < 4; ++n)
      b[n] = *(const short8*)(lds + 4096 + (n * 16 + ln) * 32 + g8);
    #pragma unroll
    for (int m = 0; m < 2; ++m)
      #pragma unroll
      for (int n = 0; n < 4; ++n)
        acc[m][n] = __builtin_amdgcn_mfma_f32_16x16x32_bf16(a[m], b[n], acc[m][n], 0, 0, 0);
  }

  #pragma unroll
  for (int m = 0; m < 2; ++m)
    #pragma unroll
    for (int n = 0; n < 4; ++n)
      #pragma unroll
      for (int j = 0; j < 4; ++j) {
        int rg = bm * 128 + w * 32 + m * 16 + l4 + j;
        int cg = bn * 64 + n * 16 + ln;
        size_t idx = (size_t)rg * DIM + cg;
        out[idx] = acc[m][n][j] + residual[idx];
      }
}

extern "C" void kernel_launch(void* const* d_in, const int* in_sizes, int n_in,
                              void* d_out, int out_size, void* d_ws, size_t ws_size,
                              hipStream_t stream) {
  const float* hidden    = (const float*)d_in[0];
  // d_in[1] = attention_mask (causal tril) — recomputed analytically
  const int*   ts        = (const int*)d_in[2];
  const float* ln_w      = (const float*)d_in[3];
  const float* attn_ln_w = (const float*)d_in[4];
  const float* wq        = (const float*)d_in[5];
  const float* wk        = (const float*)d_in[6];
  const float* wv        = (const float*)d_in[7];
  const float* wu        = (const float*)d_in[8];
  const float* wo        = (const float*)d_in[9];
  const float* ts_w      = (const float*)d_in[10];
  const float* pos_w     = (const float*)d_in[11];

  // OUTPUTS ARE FLOAT32: out [4,1024,512] then attn [4,8,1024,1024]
  float* out  = (float*)d_out;
  float* attn = out + 2097152;

  // workspace (~48 MiB < proven 56 MiB)
  bf16* wb    = (bf16*)d_ws;           // 5 * 512*512
  bf16* hb    = wb + 5 * DIM * DIM;    // [4096,512]
  bf16* q     = hb + 2097152;          // [b,h,l,d]
  bf16* k     = q + 2097152;
  bf16* v     = k + 2097152;           // [b,h,l,d]
  bf16* vT    = v + 2097152;           // [b,h,d,l]
  bf16* u     = vT + 2097152;          // [4096,512]
  bf16* gated = u + 2097152;           // [4096,512]
  float* ao0  = (float*)(gated + 2097152);  // [4096,512] f32
  float* ao1  = ao0 + 2097152;              // [4096,512] f32

  convert_w_k<<<dim3(256, 5), 256, 0, stream>>>(wq, wk, wv, wu, wo, wb);
  rmsnorm_k<<<4096, 64, 0, stream>>>(hidden, ln_w, hb);
  gemm_qkvu_k<<<dim3(128, 4), 256, 0, stream>>>(hb, wb, q, k, v, u);
  transpose_v_k<<<dim3(16, 32), 256, 0, stream>>>(v, vT);
  attn_fused_k<<<dim3(8, 32, 2), 256, 0, stream>>>(q, k, vT, ts, ts_w, pos_w, attn, ao0, ao1);
  gated_k<<<4096, 64, 0, stream>>>(ao0, ao1, u, attn_ln_w, gated);
  gemm_out_k<<<256, 256, 0, stream>>>(gated, wb + 4 * DIM * DIM, hidden, out);
}

// Round 9
// 120.939 us; speedup vs baseline: 1.2543x; 1.2543x over previous
//
#include <hip/hip_runtime.h>
#include <hip/hip_bf16.h>

typedef __hip_bfloat16 bf16;
typedef __attribute__((ext_vector_type(8))) short short8;
typedef __attribute__((ext_vector_type(4))) float f32x4;

#define SL 1024
#define DIM 512
#define NH 8
#define HD 64
#define NBUCK 128

__device__ __forceinline__ float silu_f(float x) { return x / (1.0f + __expf(-x)); }

__device__ __forceinline__ short f2bf(float x) {
  bf16 b = __float2bfloat16(x);
  return *reinterpret_cast<short*>(&b);
}

__device__ __forceinline__ void gld_lds16(const void* g, void* l) {
  __builtin_amdgcn_global_load_lds(
      (const __attribute__((address_space(1))) void*)g,
      (__attribute__((address_space(3))) void*)l, 16, 0, 0);
}

// ---------- weight f32 -> bf16 ----------
__global__ void convert_w_k(const float* __restrict__ s0, const float* __restrict__ s1,
                            const float* __restrict__ s2, const float* __restrict__ s3,
                            const float* __restrict__ s4, bf16* __restrict__ dst) {
  int wsel = blockIdx.y;
  const float* src = wsel == 0 ? s0 : wsel == 1 ? s1 : wsel == 2 ? s2 : wsel == 3 ? s3 : s4;
  int i = (blockIdx.x * 256 + threadIdx.x) * 4;
  float4 v = *(const float4*)(src + i);
  bf16* d = dst + (size_t)wsel * DIM * DIM + i;
  d[0] = __float2bfloat16(v.x);
  d[1] = __float2bfloat16(v.y);
  d[2] = __float2bfloat16(v.z);
  d[3] = __float2bfloat16(v.w);
}

// ---------- rmsnorm(hidden) -> bf16 h ----------
__global__ void rmsnorm_k(const float* __restrict__ x, const float* __restrict__ w,
                          bf16* __restrict__ out) {
  int row = blockIdx.x, l = threadIdx.x;  // 64 threads
  const float4* xr = (const float4*)(x + (size_t)row * DIM);
  float4 v0 = xr[l], v1 = xr[l + 64];
  float s = v0.x*v0.x + v0.y*v0.y + v0.z*v0.z + v0.w*v0.w
          + v1.x*v1.x + v1.y*v1.y + v1.z*v1.z + v1.w*v1.w;
  #pragma unroll
  for (int o = 32; o; o >>= 1) s += __shfl_xor(s, o);
  float sc = rsqrtf(s * (1.0f / DIM) + 1e-6f);
  bf16* orow = out + (size_t)row * DIM;
  int c0 = l * 4, c1 = 256 + l * 4;
  orow[c0 + 0] = __float2bfloat16(v0.x * sc * w[c0 + 0]);
  orow[c0 + 1] = __float2bfloat16(v0.y * sc * w[c0 + 1]);
  orow[c0 + 2] = __float2bfloat16(v0.z * sc * w[c0 + 2]);
  orow[c0 + 3] = __float2bfloat16(v0.w * sc * w[c0 + 3]);
  orow[c1 + 0] = __float2bfloat16(v1.x * sc * w[c1 + 0]);
  orow[c1 + 1] = __float2bfloat16(v1.y * sc * w[c1 + 1]);
  orow[c1 + 2] = __float2bfloat16(v1.z * sc * w[c1 + 2]);
  orow[c1 + 3] = __float2bfloat16(v1.w * sc * w[c1 + 3]);
}

// ---------- shared 128x128 GEMM core, swizzled LDS (4-chunk rows: c ^= row&3) ----------
__device__ __forceinline__ void gemm128_core(const bf16* __restrict__ A,
                                             const bf16* __restrict__ Bt,
                                             short* lds, int bm, int bn,
                                             f32x4 acc[4][4]) {
  int t = threadIdx.x, w = t >> 6, l = t & 63;
  int ln = l & 15;
  int wr = (w >> 1) * 64, wc = (w & 1) * 64;
  int scol = ((l & 3) ^ ((l >> 2) & 3)) * 8;   // pre-swizzled source chunk
  for (int kt = 0; kt < 16; ++kt) {
    if (kt) __syncthreads();
    #pragma unroll
    for (int i = 0; i < 4; ++i) {
      int s = i * 4 + w;                 // 0..15; 0-7 = A tile, 8-15 = B tile
      int row = s * 16 + (l >> 2);       // within 0..255
      int col = kt * 32 + scol;
      const bf16* gsrc = (s < 8)
          ? (A  + (size_t)(bm * 128 + row) * DIM + col)
          : (Bt + (size_t)(bn * 128 + row - 128) * DIM + col);
      gld_lds16(gsrc, lds + s * 512 + l * 8);
    }
    __syncthreads();
    int rc = ((l >> 4) ^ (ln & 3)) * 8;        // swizzled read chunk
    short8 a[4], b[4];
    #pragma unroll
    for (int m = 0; m < 4; ++m)
      a[m] = *(const short8*)(lds + (wr + m * 16 + ln) * 32 + rc);
    #pragma unroll
    for (int n = 0; n < 4; ++n)
      b[n] = *(const short8*)(lds + 4096 + (wc + n * 16 + ln) * 32 + rc);
    #pragma unroll
    for (int m = 0; m < 4; ++m)
      #pragma unroll
      for (int n = 0; n < 4; ++n)
        acc[m][n] = __builtin_amdgcn_mfma_f32_16x16x32_bf16(a[m], b[n], acc[m][n], 0, 0, 0);
  }
}

// ---------- q,k,v,u = silu(h @ W^T); q/k/v in [b,h,l,d], u row-major ----------
__global__ __launch_bounds__(256) void gemm_qkvu_k(const bf16* __restrict__ hb,
                                                   const bf16* __restrict__ wb,
                                                   bf16* __restrict__ q, bf16* __restrict__ k,
                                                   bf16* __restrict__ v, bf16* __restrict__ u) {
  __shared__ __align__(16) short lds[8192];
  int mode = blockIdx.y;
  int bm = blockIdx.x >> 2, bn = blockIdx.x & 3;
  f32x4 acc[4][4];
  #pragma unroll
  for (int m = 0; m < 4; ++m)
    #pragma unroll
    for (int n = 0; n < 4; ++n) { f32x4 z = {0.f, 0.f, 0.f, 0.f}; acc[m][n] = z; }
  gemm128_core(hb, wb + (size_t)mode * DIM * DIM, lds, bm, bn, acc);

  int t = threadIdx.x, w = t >> 6, l = t & 63;
  int ln = l & 15, l4 = (l >> 4) * 4;
  int wr = (w >> 1) * 64, wc = (w & 1) * 64;
  bf16* qkv = mode == 0 ? q : mode == 1 ? k : v;
  #pragma unroll
  for (int m = 0; m < 4; ++m)
    #pragma unroll
    for (int n = 0; n < 4; ++n)
      #pragma unroll
      for (int j = 0; j < 4; ++j) {
        int rg = bm * 128 + wr + m * 16 + l4 + j;
        int cg = bn * 128 + wc + n * 16 + ln;
        bf16 val = __float2bfloat16(silu_f(acc[m][n][j]));
        int b = rg >> 10, li = rg & 1023, hh = cg >> 6, dd = cg & 63;
        if (mode <= 2) qkv[((size_t)(b * NH + hh) * SL + li) * HD + dd] = val;
        else           u[(size_t)rg * DIM + cg] = val;
      }
}

// ---------- vT[b,h,d,l] = transpose(v[b,h,l,d]) ----------
__global__ __launch_bounds__(256) void transpose_v_k(const bf16* __restrict__ v,
                                                     bf16* __restrict__ vT) {
  int bh = blockIdx.y, t0 = blockIdx.x * 64;
  int t = threadIdx.x;
  __shared__ short ldsT[64 * 65];
  const bf16* vb = v + (size_t)bh * SL * HD;
  bf16* vtb = vT + (size_t)bh * HD * SL;
  int r = t >> 2, c = (t & 3) * 16;
  short8 x0 = *(const short8*)(vb + (size_t)(t0 + r) * HD + c);
  short8 x1 = *(const short8*)(vb + (size_t)(t0 + r) * HD + c + 8);
  #pragma unroll
  for (int qq = 0; qq < 8; ++qq) {
    ldsT[r * 65 + c + qq] = x0[qq];
    ldsT[r * 65 + c + 8 + qq] = x1[qq];
  }
  __syncthreads();
  int d = t >> 2, lc = (t & 3) * 16;
  short8 y0, y1;
  #pragma unroll
  for (int qq = 0; qq < 8; ++qq) {
    y0[qq] = ldsT[(lc + qq) * 65 + d];
    y1[qq] = ldsT[(lc + 8 + qq) * 65 + d];
  }
  bf16* dst = vtb + (size_t)d * SL + t0 + lc;
  *(short8*)dst = y0;
  *(short8*)(dst + 8) = y1;
}

// ---------- attn = silu(q k^T + bias)/L, lower tiles + folded zero tiles ----------
// q/k tiles [128][64]-short (8-chunk rows): swizzle c ^= row&7
__global__ __launch_bounds__(256) void qk_attn_k(const bf16* __restrict__ q,
                                                 const bf16* __restrict__ k,
                                                 const int* __restrict__ ts,
                                                 const float* __restrict__ ts_w,
                                                 const float* __restrict__ pos_w,
                                                 float* __restrict__ attn) {
  int bh = blockIdx.y, x = blockIdx.x;
  int ti = 0, accx = 0;
  while (accx + ti + 1 <= x) { accx += ti + 1; ++ti; }
  int tj = x - accx;                   // tj <= ti
  int t = threadIdx.x, w = t >> 6, l = t & 63;
  int ln = l & 15, l4 = (l >> 4) * 4;
  int wr = (w >> 1) * 64, wc = (w & 1) * 64;
  float* arow = attn + (size_t)bh * SL * SL;

  __shared__ __align__(16) short lds[16384];  // q tile [128][64], k tile [128][64]
  __shared__ float tw_l[NBUCK + 1];
  __shared__ float pw_l[255];
  __shared__ int tsi_l[128], tsj_l[128];

  const int* tsb = ts + (size_t)(bh >> 3) * SL;
  if (t < NBUCK + 1) tw_l[t] = ts_w[t];
  if (t < 255) pw_l[t] = pos_w[896 + (tj - ti) * 128 + t];
  if (t < 128) tsi_l[t] = tsb[min(ti * 128 + t + 1, SL - 1)];
  else         tsj_l[t - 128] = tsb[tj * 128 + (t - 128)];

  #pragma unroll
  for (int i = 0; i < 8; ++i) {
    int s = i * 4 + w;                 // 0..31; 0-15 q, 16-31 k
    int row = (s & 15) * 8 + (l >> 3);
    int col = ((l & 7) ^ (l >> 3)) * 8;   // pre-swizzled source (row&7 == l>>3)
    const bf16* g = (s < 16)
        ? (q + (size_t)bh * SL * HD + (size_t)(ti * 128 + row) * HD + col)
        : (k + (size_t)bh * SL * HD + (size_t)(tj * 128 + row) * HD + col);
    gld_lds16(g, lds + s * 512 + l * 8);
  }
  __syncthreads();

  f32x4 acc[4][4];
  #pragma unroll
  for (int m = 0; m < 4; ++m)
    #pragma unroll
    for (int n = 0; n < 4; ++n) { f32x4 z = {0.f, 0.f, 0.f, 0.f}; acc[m][n] = z; }
  #pragma unroll
  for (int kk = 0; kk < 2; ++kk) {        // chunk base 0 / 4
    short8 a[4], b[4];
    #pragma unroll
    for (int m = 0; m < 4; ++m) {
      int row = wr + m * 16 + ln;
      int c = ((kk * 4 + (l >> 4)) ^ (row & 7)) * 8;
      a[m] = *(const short8*)(lds + row * 64 + c);
    }
    #pragma unroll
    for (int n = 0; n < 4; ++n) {
      int row = wc + n * 16 + ln;
      int c = ((kk * 4 + (l >> 4)) ^ (row & 7)) * 8;
      b[n] = *(const short8*)(lds + 8192 + row * 64 + c);
    }
    #pragma unroll
    for (int m = 0; m < 4; ++m)
      #pragma unroll
      for (int n = 0; n < 4; ++n)
        acc[m][n] = __builtin_amdgcn_mfma_f32_16x16x32_bf16(a[m], b[n], acc[m][n], 0, 0, 0);
  }

  const float LSC = 2.30281455f;       // ln2 / 0.301
  #pragma unroll
  for (int m = 0; m < 4; ++m)
    #pragma unroll
    for (int j = 0; j < 4; ++j) {
      int il = wr + m * 16 + l4 + j;
      int tsi = tsi_l[il];
      int i = ti * 128 + il;
      #pragma unroll
      for (int n = 0; n < 4; ++n) {
        int jl = wc + n * 16 + ln;
        int jj = tj * 128 + jl;
        float v = acc[m][n][j];
        int dt = tsi - tsj_l[jl];
        float adf = fmaxf(fabsf((float)dt), 1.0f);
        int bucket = (int)(__log2f(adf) * LSC);
        bucket = bucket < 0 ? 0 : (bucket > NBUCK ? NBUCK : bucket);
        float bias = tw_l[bucket] + pw_l[jl - il + 127];
        float o = (jj <= i) ? silu_f(v + bias) * (1.0f / (float)SL) : 0.0f;
        arow[(size_t)i * SL + jj] = o;
      }
    }

  // folded zero-fill of one strict-upper tile (28 tiles over blocks 0..27)
  if (x < 28) {
    int zi = 0, acc2 = 0;
    while (acc2 + (7 - zi) <= x) { acc2 += 7 - zi; ++zi; }
    int zj = zi + 1 + (x - acc2);
    float4 z4 = make_float4(0.f, 0.f, 0.f, 0.f);
    #pragma unroll
    for (int rep = 0; rep < 16; ++rep) {
      int flat = rep * 256 + t;
      int row = flat >> 5, c4 = flat & 31;
      *(float4*)(arow + (size_t)(zi * 128 + row) * SL + zj * 128 + c4 * 4) = z4;
    }
  }
}

// ---------- partial attn_out (K-split=2); [_][32]-short tiles: c ^= row&3 ----------
__global__ __launch_bounds__(256) void pv_k(const float* __restrict__ attn,
                                            const bf16* __restrict__ vT,
                                            float* __restrict__ ao0,
                                            float* __restrict__ ao1) {
  int bh = blockIdx.y, bm = blockIdx.x, sp = blockIdx.z;
  int t = threadIdx.x, w = t >> 6, l = t & 63;
  int ln = l & 15, l4 = (l >> 4) * 4;
  __shared__ __align__(16) short lds[6144];  // A tile [128][32] bf16, B tile [64][32]
  const float* arow = attn + (size_t)bh * SL * SL;
  const bf16* vrow = vT + (size_t)bh * HD * SL;
  f32x4 acc[2][4];
  #pragma unroll
  for (int m = 0; m < 2; ++m)
    #pragma unroll
    for (int n = 0; n < 4; ++n) { f32x4 z = {0.f, 0.f, 0.f, 0.f}; acc[m][n] = z; }

  int swd = ((l & 3) ^ ((l >> 2) & 3)) * 8;  // swizzled dest/source chunk (row&3 == (l>>2)&3)
  int klo = sp * (bm + 1) * 2;         // half of ktmax=(bm+1)*4
  int khi = (sp + 1) * (bm + 1) * 2;
  for (int kt = klo; kt < khi; ++kt) {
    if (kt > klo) __syncthreads();
    // A tile: 8 slices from f32 attn, reg-converted to bf16, swizzled ds_write
    {
      int s = w * 2;                   // wave w covers slices {2w, 2w+1}
      #pragma unroll
      for (int ss = 0; ss < 2; ++ss, ++s) {
        int row = s * 16 + (l >> 2);
        int col = kt * 32 + (l & 3) * 8;
        const float* g = arow + (size_t)(bm * 128 + row) * SL + col;
        float4 f0 = *(const float4*)g;
        float4 f1 = *(const float4*)(g + 4);
        short8 vv;
        vv[0] = f2bf(f0.x); vv[1] = f2bf(f0.y); vv[2] = f2bf(f0.z); vv[3] = f2bf(f0.w);
        vv[4] = f2bf(f1.x); vv[5] = f2bf(f1.y); vv[6] = f2bf(f1.z); vv[7] = f2bf(f1.w);
        *(short8*)(lds + row * 32 + swd) = vv;
      }
    }
    // B tile: 4 slices from bf16 vT via async LDS, pre-swizzled source
    {
      int s = 8 + w;
      int r2 = (s - 8) * 16 + (l >> 2);
      int col = kt * 32 + swd;
      gld_lds16(vrow + (size_t)r2 * SL + col, lds + s * 512 + l * 8);
    }
    __syncthreads();
    int rc0 = (l >> 4);
    short8 a[2], b[4];
    #pragma unroll
    for (int m = 0; m < 2; ++m) {
      int row = w * 32 + m * 16 + ln;
      a[m] = *(const short8*)(lds + row * 32 + ((rc0 ^ (row & 3)) * 8));
    }
    #pragma unroll
    for (int n = 0; n < 4; ++n) {
      int row = n * 16 + ln;
      b[n] = *(const short8*)(lds + 4096 + row * 32 + ((rc0 ^ (row & 3)) * 8));
    }
    #pragma unroll
    for (int m = 0; m < 2; ++m)
      #pragma unroll
      for (int n = 0; n < 4; ++n)
        acc[m][n] = __builtin_amdgcn_mfma_f32_16x16x32_bf16(a[m], b[n], acc[m][n], 0, 0, 0);
  }

  float* aop = sp == 0 ? ao0 : ao1;
  int b = bh >> 3, hh = bh & 7;
  #pragma unroll
  for (int m = 0; m < 2; ++m)
    #pragma unroll
    for (int n = 0; n < 4; ++n)
      #pragma unroll
      for (int j = 0; j < 4; ++j) {
        int i = bm * 128 + w * 32 + m * 16 + l4 + j;
        int dd = n * 16 + ln;
        aop[((size_t)(b * SL + i)) * DIM + hh * HD + dd] = acc[m][n][j];
      }
}

// ---------- gated = u * rmsnorm(ao0+ao1) * attn_ln_w ----------
__global__ void gated_k(const float* __restrict__ ao0, const float* __restrict__ ao1,
                        const bf16* __restrict__ u,
                        const float* __restrict__ w, bf16* __restrict__ g) {
  int row = blockIdx.x, l = threadIdx.x;  // 64 threads
  const float4* ar0 = (const float4*)(ao0 + (size_t)row * DIM);
  const float4* ar1 = (const float4*)(ao1 + (size_t)row * DIM);
  float4 p0 = ar0[l], p1 = ar1[l], p2 = ar0[l + 64], p3 = ar1[l + 64];
  float4 a0 = make_float4(p0.x + p1.x, p0.y + p1.y, p0.z + p1.z, p0.w + p1.w);
  float4 a1 = make_float4(p2.x + p3.x, p2.y + p3.y, p2.z + p3.z, p2.w + p3.w);
  float s = a0.x*a0.x + a0.y*a0.y + a0.z*a0.z + a0.w*a0.w
          + a1.x*a1.x + a1.y*a1.y + a1.z*a1.z + a1.w*a1.w;
  #pragma unroll
  for (int o = 32; o; o >>= 1) s += __shfl_xor(s, o);
  float sc = rsqrtf(s * (1.0f / DIM) + 1e-6f);
  const bf16* ur = u + (size_t)row * DIM;
  bf16* gr = g + (size_t)row * DIM;
  int c0 = l * 4, c1 = 256 + l * 4;
  gr[c0 + 0] = __float2bfloat16(__bfloat162float(ur[c0 + 0]) * a0.x * sc * w[c0 + 0]);
  gr[c0 + 1] = __float2bfloat16(__bfloat162float(ur[c0 + 1]) * a0.y * sc * w[c0 + 1]);
  gr[c0 + 2] = __float2bfloat16(__bfloat162float(ur[c0 + 2]) * a0.z * sc * w[c0 + 2]);
  gr[c0 + 3] = __float2bfloat16(__bfloat162float(ur[c0 + 3]) * a0.w * sc * w[c0 + 3]);
  gr[c1 + 0] = __float2bfloat16(__bfloat162float(ur[c1 + 0]) * a1.x * sc * w[c1 + 0]);
  gr[c1 + 1] = __float2bfloat16(__bfloat162float(ur[c1 + 1]) * a1.y * sc * w[c1 + 1]);
  gr[c1 + 2] = __float2bfloat16(__bfloat162float(ur[c1 + 2]) * a1.z * sc * w[c1 + 2]);
  gr[c1 + 3] = __float2bfloat16(__bfloat162float(ur[c1 + 3]) * a1.w * sc * w[c1 + 3]);
}

// ---------- out = residual + gated @ wo^T, 128x64 tiles, swizzled ----------
__global__ __launch_bounds__(256) void gemm_out_k(const bf16* __restrict__ gated,
                                                  const bf16* __restrict__ wob,
                                                  const float* __restrict__ residual,
                                                  float* __restrict__ out) {
  int bm = blockIdx.x >> 3, bn = blockIdx.x & 7;
  int t = threadIdx.x, w = t >> 6, l = t & 63;
  int ln = l & 15, l4 = (l >> 4) * 4;
  __shared__ __align__(16) short lds[6144];  // A tile [128][32], B tile [64][32]
  f32x4 acc[2][4];
  #pragma unroll
  for (int m = 0; m < 2; ++m)
    #pragma unroll
    for (int n = 0; n < 4; ++n) { f32x4 z = {0.f, 0.f, 0.f, 0.f}; acc[m][n] = z; }

  int swd = ((l & 3) ^ ((l >> 2) & 3)) * 8;
  for (int kt = 0; kt < 16; ++kt) {
    if (kt) __syncthreads();
    #pragma unroll
    for (int i = 0; i < 3; ++i) {
      int s = i * 4 + w;               // 0..11; 0-7 A, 8-11 B
      int col = kt * 32 + swd;
      const bf16* g;
      if (s < 8) { int row = s * 16 + (l >> 2); g = gated + (size_t)(bm * 128 + row) * DIM + col; }
      else       { int r2 = (s - 8) * 16 + (l >> 2); g = wob + (size_t)(bn * 64 + r2) * DIM + col; }
      gld_lds16(g, lds + s * 512 + l * 8);
    }
    __syncthreads();
    int rc0 = (l >> 4);
    short8 a[2], b[4];
    #pragma unroll
    for (int m = 0; m < 2; ++m) {
      int row = w * 32 + m * 16 + ln;
      a[m] = *(const short8*)(lds + row * 32 + ((rc0 ^ (row & 3)) * 8));
    }
    #pragma unroll
    for (int n = 0; n < 4; ++n) {
      int row = n * 16 + ln;
      b[n] = *(const short8*)(lds + 4096 + row * 32 + ((rc0 ^ (row & 3)) * 8));
    }
    #pragma unroll
    for (int m = 0; m < 2; ++m)
      #pragma unroll
      for (int n = 0; n < 4; ++n)
        acc[m][n] = __builtin_amdgcn_mfma_f32_16x16x32_bf16(a[m], b[n], acc[m][n], 0, 0, 0);
  }

  #pragma unroll
  for (int m = 0; m < 2; ++m)
    #pragma unroll
    for (int n = 0; n < 4; ++n)
      #pragma unroll
      for (int j = 0; j < 4; ++j) {
        int rg = bm * 128 + w * 32 + m * 16 + l4 + j;
        int cg = bn * 64 + n * 16 + ln;
        size_t idx = (size_t)rg * DIM + cg;
        out[idx] = acc[m][n][j] + residual[idx];
      }
}

extern "C" void kernel_launch(void* const* d_in, const int* in_sizes, int n_in,
                              void* d_out, int out_size, void* d_ws, size_t ws_size,
                              hipStream_t stream) {
  const float* hidden    = (const float*)d_in[0];
  // d_in[1] = attention_mask (causal tril) — recomputed analytically
  const int*   ts        = (const int*)d_in[2];
  const float* ln_w      = (const float*)d_in[3];
  const float* attn_ln_w = (const float*)d_in[4];
  const float* wq        = (const float*)d_in[5];
  const float* wk        = (const float*)d_in[6];
  const float* wv        = (const float*)d_in[7];
  const float* wu        = (const float*)d_in[8];
  const float* wo        = (const float*)d_in[9];
  const float* ts_w      = (const float*)d_in[10];
  const float* pos_w     = (const float*)d_in[11];

  // OUTPUTS ARE FLOAT32: out [4,1024,512] then attn [4,8,1024,1024]
  float* out  = (float*)d_out;
  float* attn = out + 2097152;

  // workspace (~48 MiB < proven 56 MiB)
  bf16* wb    = (bf16*)d_ws;           // 5 * 512*512
  bf16* hb    = wb + 5 * DIM * DIM;    // [4096,512]
  bf16* q     = hb + 2097152;          // [b,h,l,d]
  bf16* k     = q + 2097152;
  bf16* v     = k + 2097152;           // [b,h,l,d]
  bf16* vT    = v + 2097152;           // [b,h,d,l]
  bf16* u     = vT + 2097152;          // [4096,512]
  bf16* gated = u + 2097152;           // [4096,512]
  float* ao0  = (float*)(gated + 2097152);  // [4096,512] f32
  float* ao1  = ao0 + 2097152;              // [4096,512] f32

  convert_w_k<<<dim3(256, 5), 256, 0, stream>>>(wq, wk, wv, wu, wo, wb);
  rmsnorm_k<<<4096, 64, 0, stream>>>(hidden, ln_w, hb);
  gemm_qkvu_k<<<dim3(128, 4), 256, 0, stream>>>(hb, wb, q, k, v, u);
  transpose_v_k<<<dim3(16, 32), 256, 0, stream>>>(v, vT);
  qk_attn_k<<<dim3(36, 32), 256, 0, stream>>>(q, k, ts, ts_w, pos_w, attn);
  pv_k<<<dim3(8, 32, 2), 256, 0, stream>>>(attn, vT, ao0, ao1);
  gated_k<<<4096, 64, 0, stream>>>(ao0, ao1, u, attn_ln_w, gated);
  gemm_out_k<<<256, 256, 0, stream>>>(gated, wb + 4 * DIM * DIM, hidden, out);
}

// Round 10
// 115.517 us; speedup vs baseline: 1.3132x; 1.0469x over previous
//
#include <hip/hip_runtime.h>
#include <hip/hip_bf16.h>

typedef __hip_bfloat16 bf16;
typedef __attribute__((ext_vector_type(8))) short short8;
typedef __attribute__((ext_vector_type(4))) float f32x4;

#define SL 1024
#define DIM 512
#define NH 8
#define HD 64
#define NBUCK 128

__device__ __forceinline__ float silu_f(float x) { return x / (1.0f + __expf(-x)); }

__device__ __forceinline__ short f2bf(float x) {
  bf16 b = __float2bfloat16(x);
  return *reinterpret_cast<short*>(&b);
}

__device__ __forceinline__ void gld_lds16(const void* g, void* l) {
  __builtin_amdgcn_global_load_lds(
      (const __attribute__((address_space(1))) void*)g,
      (__attribute__((address_space(3))) void*)l, 16, 0, 0);
}

// ---------- fused prep: weights f32->bf16 (blocks 0..1279) + rmsnorm (blocks 1280..2303) ----------
__global__ __launch_bounds__(256) void prep_k(const float* __restrict__ s0, const float* __restrict__ s1,
                                              const float* __restrict__ s2, const float* __restrict__ s3,
                                              const float* __restrict__ s4, bf16* __restrict__ wdst,
                                              const float* __restrict__ hidden, const float* __restrict__ ln_w,
                                              bf16* __restrict__ hb) {
  int bx = blockIdx.x;
  if (bx < 1280) {
    int wsel = bx >> 8;
    const float* src = wsel == 0 ? s0 : wsel == 1 ? s1 : wsel == 2 ? s2 : wsel == 3 ? s3 : s4;
    int i = ((bx & 255) * 256 + threadIdx.x) * 4;
    float4 v = *(const float4*)(src + i);
    bf16* d = wdst + (size_t)wsel * DIM * DIM + i;
    d[0] = __float2bfloat16(v.x);
    d[1] = __float2bfloat16(v.y);
    d[2] = __float2bfloat16(v.z);
    d[3] = __float2bfloat16(v.w);
  } else {
    int row = (bx - 1280) * 4 + (threadIdx.x >> 6);  // one row per wave
    int l = threadIdx.x & 63;
    const float4* xr = (const float4*)(hidden + (size_t)row * DIM);
    float4 v0 = xr[l], v1 = xr[l + 64];
    float s = v0.x*v0.x + v0.y*v0.y + v0.z*v0.z + v0.w*v0.w
            + v1.x*v1.x + v1.y*v1.y + v1.z*v1.z + v1.w*v1.w;
    #pragma unroll
    for (int o = 32; o; o >>= 1) s += __shfl_xor(s, o);
    float sc = rsqrtf(s * (1.0f / DIM) + 1e-6f);
    bf16* orow = hb + (size_t)row * DIM;
    int c0 = l * 4, c1 = 256 + l * 4;
    orow[c0 + 0] = __float2bfloat16(v0.x * sc * ln_w[c0 + 0]);
    orow[c0 + 1] = __float2bfloat16(v0.y * sc * ln_w[c0 + 1]);
    orow[c0 + 2] = __float2bfloat16(v0.z * sc * ln_w[c0 + 2]);
    orow[c0 + 3] = __float2bfloat16(v0.w * sc * ln_w[c0 + 3]);
    orow[c1 + 0] = __float2bfloat16(v1.x * sc * ln_w[c1 + 0]);
    orow[c1 + 1] = __float2bfloat16(v1.y * sc * ln_w[c1 + 1]);
    orow[c1 + 2] = __float2bfloat16(v1.z * sc * ln_w[c1 + 2]);
    orow[c1 + 3] = __float2bfloat16(v1.w * sc * ln_w[c1 + 3]);
  }
}

// ---------- shared 128x128 GEMM core, swizzled LDS (4-chunk rows: c ^= row&3) ----------
__device__ __forceinline__ void gemm128_core(const bf16* __restrict__ A,
                                             const bf16* __restrict__ Bt,
                                             short* lds, int bm, int bn,
                                             f32x4 acc[4][4]) {
  int t = threadIdx.x, w = t >> 6, l = t & 63;
  int ln = l & 15;
  int wr = (w >> 1) * 64, wc = (w & 1) * 64;
  int scol = ((l & 3) ^ ((l >> 2) & 3)) * 8;   // pre-swizzled source chunk
  for (int kt = 0; kt < 16; ++kt) {
    if (kt) __syncthreads();
    #pragma unroll
    for (int i = 0; i < 4; ++i) {
      int s = i * 4 + w;                 // 0..15; 0-7 = A tile, 8-15 = B tile
      int row = s * 16 + (l >> 2);       // within 0..255
      int col = kt * 32 + scol;
      const bf16* gsrc = (s < 8)
          ? (A  + (size_t)(bm * 128 + row) * DIM + col)
          : (Bt + (size_t)(bn * 128 + row - 128) * DIM + col);
      gld_lds16(gsrc, lds + s * 512 + l * 8);
    }
    __syncthreads();
    int rc = ((l >> 4) ^ (ln & 3)) * 8;        // swizzled read chunk
    short8 a[4], b[4];
    #pragma unroll
    for (int m = 0; m < 4; ++m)
      a[m] = *(const short8*)(lds + (wr + m * 16 + ln) * 32 + rc);
    #pragma unroll
    for (int n = 0; n < 4; ++n)
      b[n] = *(const short8*)(lds + 4096 + (wc + n * 16 + ln) * 32 + rc);
    #pragma unroll
    for (int m = 0; m < 4; ++m)
      #pragma unroll
      for (int n = 0; n < 4; ++n)
        acc[m][n] = __builtin_amdgcn_mfma_f32_16x16x32_bf16(a[m], b[n], acc[m][n], 0, 0, 0);
  }
}

// ---------- q,k,v,u = silu(h @ W^T); q/k/v in [b,h,l,d], u row-major ----------
// XCD swizzle: bm = x%32 so all bn-blocks of one bm land on one XCD (x%8 = bm%8)
__global__ __launch_bounds__(256) void gemm_qkvu_k(const bf16* __restrict__ hb,
                                                   const bf16* __restrict__ wb,
                                                   bf16* __restrict__ q, bf16* __restrict__ k,
                                                   bf16* __restrict__ v, bf16* __restrict__ u) {
  __shared__ __align__(16) short lds[8192];
  int mode = blockIdx.y;
  int bm = blockIdx.x & 31, bn = blockIdx.x >> 5;
  f32x4 acc[4][4];
  #pragma unroll
  for (int m = 0; m < 4; ++m)
    #pragma unroll
    for (int n = 0; n < 4; ++n) { f32x4 z = {0.f, 0.f, 0.f, 0.f}; acc[m][n] = z; }
  gemm128_core(hb, wb + (size_t)mode * DIM * DIM, lds, bm, bn, acc);

  int t = threadIdx.x, w = t >> 6, l = t & 63;
  int ln = l & 15, l4 = (l >> 4) * 4;
  int wr = (w >> 1) * 64, wc = (w & 1) * 64;
  bf16* qkv = mode == 0 ? q : mode == 1 ? k : v;
  #pragma unroll
  for (int m = 0; m < 4; ++m)
    #pragma unroll
    for (int n = 0; n < 4; ++n)
      #pragma unroll
      for (int j = 0; j < 4; ++j) {
        int rg = bm * 128 + wr + m * 16 + l4 + j;
        int cg = bn * 128 + wc + n * 16 + ln;
        bf16 val = __float2bfloat16(silu_f(acc[m][n][j]));
        int b = rg >> 10, li = rg & 1023, hh = cg >> 6, dd = cg & 63;
        if (mode <= 2) qkv[((size_t)(b * NH + hh) * SL + li) * HD + dd] = val;
        else           u[(size_t)rg * DIM + cg] = val;
      }
}

// ---------- vT[b,h,d,l] = transpose(v[b,h,l,d]) ----------
__global__ __launch_bounds__(256) void transpose_v_k(const bf16* __restrict__ v,
                                                     bf16* __restrict__ vT) {
  int bh = blockIdx.y, t0 = blockIdx.x * 64;
  int t = threadIdx.x;
  __shared__ short ldsT[64 * 65];
  const bf16* vb = v + (size_t)bh * SL * HD;
  bf16* vtb = vT + (size_t)bh * HD * SL;
  int r = t >> 2, c = (t & 3) * 16;
  short8 x0 = *(const short8*)(vb + (size_t)(t0 + r) * HD + c);
  short8 x1 = *(const short8*)(vb + (size_t)(t0 + r) * HD + c + 8);
  #pragma unroll
  for (int qq = 0; qq < 8; ++qq) {
    ldsT[r * 65 + c + qq] = x0[qq];
    ldsT[r * 65 + c + 8 + qq] = x1[qq];
  }
  __syncthreads();
  int d = t >> 2, lc = (t & 3) * 16;
  short8 y0, y1;
  #pragma unroll
  for (int qq = 0; qq < 8; ++qq) {
    y0[qq] = ldsT[(lc + qq) * 65 + d];
    y1[qq] = ldsT[(lc + 8 + qq) * 65 + d];
  }
  bf16* dst = vtb + (size_t)d * SL + t0 + lc;
  *(short8*)dst = y0;
  *(short8*)(dst + 8) = y1;
}

// ---------- attn = silu(q k^T + bias)/L, lower tiles + folded zero tiles ----------
__global__ __launch_bounds__(256) void qk_attn_k(const bf16* __restrict__ q,
                                                 const bf16* __restrict__ k,
                                                 const int* __restrict__ ts,
                                                 const float* __restrict__ ts_w,
                                                 const float* __restrict__ pos_w,
                                                 float* __restrict__ attn) {
  int bh = blockIdx.y, x = blockIdx.x;
  int ti = 0, accx = 0;
  while (accx + ti + 1 <= x) { accx += ti + 1; ++ti; }
  int tj = x - accx;                   // tj <= ti
  int t = threadIdx.x, w = t >> 6, l = t & 63;
  int ln = l & 15, l4 = (l >> 4) * 4;
  int wr = (w >> 1) * 64, wc = (w & 1) * 64;
  float* arow = attn + (size_t)bh * SL * SL;

  __shared__ __align__(16) short lds[16384];  // q tile [128][64], k tile [128][64]
  __shared__ float tw_l[NBUCK + 1];
  __shared__ float pw_l[255];
  __shared__ int tsi_l[128], tsj_l[128];

  const int* tsb = ts + (size_t)(bh >> 3) * SL;
  if (t < NBUCK + 1) tw_l[t] = ts_w[t];
  if (t < 255) pw_l[t] = pos_w[896 + (tj - ti) * 128 + t];
  if (t < 128) tsi_l[t] = tsb[min(ti * 128 + t + 1, SL - 1)];
  else         tsj_l[t - 128] = tsb[tj * 128 + (t - 128)];

  #pragma unroll
  for (int i = 0; i < 8; ++i) {
    int s = i * 4 + w;                 // 0..31; 0-15 q, 16-31 k
    int row = (s & 15) * 8 + (l >> 3);
    int col = ((l & 7) ^ (l >> 3)) * 8;   // pre-swizzled source (row&7 == l>>3)
    const bf16* g = (s < 16)
        ? (q + (size_t)bh * SL * HD + (size_t)(ti * 128 + row) * HD + col)
        : (k + (size_t)bh * SL * HD + (size_t)(tj * 128 + row) * HD + col);
    gld_lds16(g, lds + s * 512 + l * 8);
  }
  __syncthreads();

  f32x4 acc[4][4];
  #pragma unroll
  for (int m = 0; m < 4; ++m)
    #pragma unroll
    for (int n = 0; n < 4; ++n) { f32x4 z = {0.f, 0.f, 0.f, 0.f}; acc[m][n] = z; }
  #pragma unroll
  for (int kk = 0; kk < 2; ++kk) {        // chunk base 0 / 4
    short8 a[4], b[4];
    #pragma unroll
    for (int m = 0; m < 4; ++m) {
      int row = wr + m * 16 + ln;
      int c = ((kk * 4 + (l >> 4)) ^ (row & 7)) * 8;
      a[m] = *(const short8*)(lds + row * 64 + c);
    }
    #pragma unroll
    for (int n = 0; n < 4; ++n) {
      int row = wc + n * 16 + ln;
      int c = ((kk * 4 + (l >> 4)) ^ (row & 7)) * 8;
      b[n] = *(const short8*)(lds + 8192 + row * 64 + c);
    }
    #pragma unroll
    for (int m = 0; m < 4; ++m)
      #pragma unroll
      for (int n = 0; n < 4; ++n)
        acc[m][n] = __builtin_amdgcn_mfma_f32_16x16x32_bf16(a[m], b[n], acc[m][n], 0, 0, 0);
  }

  const float LSC = 2.30281455f;       // ln2 / 0.301
  #pragma unroll
  for (int m = 0; m < 4; ++m)
    #pragma unroll
    for (int j = 0; j < 4; ++j) {
      int il = wr + m * 16 + l4 + j;
      int tsi = tsi_l[il];
      int i = ti * 128 + il;
      #pragma unroll
      for (int n = 0; n < 4; ++n) {
        int jl = wc + n * 16 + ln;
        int jj = tj * 128 + jl;
        float v = acc[m][n][j];
        int dt = tsi - tsj_l[jl];
        float adf = fmaxf(fabsf((float)dt), 1.0f);
        int bucket = (int)(__log2f(adf) * LSC);
        bucket = bucket < 0 ? 0 : (bucket > NBUCK ? NBUCK : bucket);
        float bias = tw_l[bucket] + pw_l[jl - il + 127];
        float o = (jj <= i) ? silu_f(v + bias) * (1.0f / (float)SL) : 0.0f;
        arow[(size_t)i * SL + jj] = o;
      }
    }

  // folded zero-fill of one strict-upper tile (28 tiles over blocks 0..27)
  if (x < 28) {
    int zi = 0, acc2 = 0;
    while (acc2 + (7 - zi) <= x) { acc2 += 7 - zi; ++zi; }
    int zj = zi + 1 + (x - acc2);
    float4 z4 = make_float4(0.f, 0.f, 0.f, 0.f);
    #pragma unroll
    for (int rep = 0; rep < 16; ++rep) {
      int flat = rep * 256 + t;
      int row = flat >> 5, c4 = flat & 31;
      *(float4*)(arow + (size_t)(zi * 128 + row) * SL + zj * 128 + c4 * 4) = z4;
    }
  }
}

// ---------- partial attn_out (K-split=2); [_][32]-short tiles: c ^= row&3 ----------
__global__ __launch_bounds__(256) void pv_k(const float* __restrict__ attn,
                                            const bf16* __restrict__ vT,
                                            float* __restrict__ ao0,
                                            float* __restrict__ ao1) {
  int bh = blockIdx.y, bm = blockIdx.x, sp = blockIdx.z;
  int t = threadIdx.x, w = t >> 6, l = t & 63;
  int ln = l & 15, l4 = (l >> 4) * 4;
  __shared__ __align__(16) short lds[6144];  // A tile [128][32] bf16, B tile [64][32]
  const float* arow = attn + (size_t)bh * SL * SL;
  const bf16* vrow = vT + (size_t)bh * HD * SL;
  f32x4 acc[2][4];
  #pragma unroll
  for (int m = 0; m < 2; ++m)
    #pragma unroll
    for (int n = 0; n < 4; ++n) { f32x4 z = {0.f, 0.f, 0.f, 0.f}; acc[m][n] = z; }

  int swd = ((l & 3) ^ ((l >> 2) & 3)) * 8;  // swizzled dest/source chunk (row&3 == (l>>2)&3)
  int klo = sp * (bm + 1) * 2;         // half of ktmax=(bm+1)*4
  int khi = (sp + 1) * (bm + 1) * 2;
  for (int kt = klo; kt < khi; ++kt) {
    if (kt > klo) __syncthreads();
    // A tile: 8 slices from f32 attn, reg-converted to bf16, swizzled ds_write
    {
      int s = w * 2;                   // wave w covers slices {2w, 2w+1}
      #pragma unroll
      for (int ss = 0; ss < 2; ++ss, ++s) {
        int row = s * 16 + (l >> 2);
        int col = kt * 32 + (l & 3) * 8;
        const float* g = arow + (size_t)(bm * 128 + row) * SL + col;
        float4 f0 = *(const float4*)g;
        float4 f1 = *(const float4*)(g + 4);
        short8 vv;
        vv[0] = f2bf(f0.x); vv[1] = f2bf(f0.y); vv[2] = f2bf(f0.z); vv[3] = f2bf(f0.w);
        vv[4] = f2bf(f1.x); vv[5] = f2bf(f1.y); vv[6] = f2bf(f1.z); vv[7] = f2bf(f1.w);
        *(short8*)(lds + row * 32 + swd) = vv;
      }
    }
    // B tile: 4 slices from bf16 vT via async LDS, pre-swizzled source
    {
      int s = 8 + w;
      int r2 = (s - 8) * 16 + (l >> 2);
      int col = kt * 32 + swd;
      gld_lds16(vrow + (size_t)r2 * SL + col, lds + s * 512 + l * 8);
    }
    __syncthreads();
    int rc0 = (l >> 4);
    short8 a[2], b[4];
    #pragma unroll
    for (int m = 0; m < 2; ++m) {
      int row = w * 32 + m * 16 + ln;
      a[m] = *(const short8*)(lds + row * 32 + ((rc0 ^ (row & 3)) * 8));
    }
    #pragma unroll
    for (int n = 0; n < 4; ++n) {
      int row = n * 16 + ln;
      b[n] = *(const short8*)(lds + 4096 + row * 32 + ((rc0 ^ (row & 3)) * 8));
    }
    #pragma unroll
    for (int m = 0; m < 2; ++m)
      #pragma unroll
      for (int n = 0; n < 4; ++n)
        acc[m][n] = __builtin_amdgcn_mfma_f32_16x16x32_bf16(a[m], b[n], acc[m][n], 0, 0, 0);
  }

  float* aop = sp == 0 ? ao0 : ao1;
  int b = bh >> 3, hh = bh & 7;
  #pragma unroll
  for (int m = 0; m < 2; ++m)
    #pragma unroll
    for (int n = 0; n < 4; ++n)
      #pragma unroll
      for (int j = 0; j < 4; ++j) {
        int i = bm * 128 + w * 32 + m * 16 + l4 + j;
        int dd = n * 16 + ln;
        aop[((size_t)(b * SL + i)) * DIM + hh * HD + dd] = acc[m][n][j];
      }
}

// ---------- gated = u * rmsnorm(ao0+ao1) * attn_ln_w ----------
__global__ void gated_k(const float* __restrict__ ao0, const float* __restrict__ ao1,
                        const bf16* __restrict__ u,
                        const float* __restrict__ w, bf16* __restrict__ g) {
  int row = blockIdx.x, l = threadIdx.x;  // 64 threads
  const float4* ar0 = (const float4*)(ao0 + (size_t)row * DIM);
  const float4* ar1 = (const float4*)(ao1 + (size_t)row * DIM);
  float4 p0 = ar0[l], p1 = ar1[l], p2 = ar0[l + 64], p3 = ar1[l + 64];
  float4 a0 = make_float4(p0.x + p1.x, p0.y + p1.y, p0.z + p1.z, p0.w + p1.w);
  float4 a1 = make_float4(p2.x + p3.x, p2.y + p3.y, p2.z + p3.z, p2.w + p3.w);
  float s = a0.x*a0.x + a0.y*a0.y + a0.z*a0.z + a0.w*a0.w
          + a1.x*a1.x + a1.y*a1.y + a1.z*a1.z + a1.w*a1.w;
  #pragma unroll
  for (int o = 32; o; o >>= 1) s += __shfl_xor(s, o);
  float sc = rsqrtf(s * (1.0f / DIM) + 1e-6f);
  const bf16* ur = u + (size_t)row * DIM;
  bf16* gr = g + (size_t)row * DIM;
  int c0 = l * 4, c1 = 256 + l * 4;
  gr[c0 + 0] = __float2bfloat16(__bfloat162float(ur[c0 + 0]) * a0.x * sc * w[c0 + 0]);
  gr[c0 + 1] = __float2bfloat16(__bfloat162float(ur[c0 + 1]) * a0.y * sc * w[c0 + 1]);
  gr[c0 + 2] = __float2bfloat16(__bfloat162float(ur[c0 + 2]) * a0.z * sc * w[c0 + 2]);
  gr[c0 + 3] = __float2bfloat16(__bfloat162float(ur[c0 + 3]) * a0.w * sc * w[c0 + 3]);
  gr[c1 + 0] = __float2bfloat16(__bfloat162float(ur[c1 + 0]) * a1.x * sc * w[c1 + 0]);
  gr[c1 + 1] = __float2bfloat16(__bfloat162float(ur[c1 + 1]) * a1.y * sc * w[c1 + 1]);
  gr[c1 + 2] = __float2bfloat16(__bfloat162float(ur[c1 + 2]) * a1.z * sc * w[c1 + 2]);
  gr[c1 + 3] = __float2bfloat16(__bfloat162float(ur[c1 + 3]) * a1.w * sc * w[c1 + 3]);
}

// ---------- out = residual + gated @ wo^T, 128x64 tiles, XCD-swizzled ----------
__global__ __launch_bounds__(256) void gemm_out_k(const bf16* __restrict__ gated,
                                                  const bf16* __restrict__ wob,
                                                  const float* __restrict__ residual,
                                                  float* __restrict__ out) {
  int bm = blockIdx.x & 31, bn = blockIdx.x >> 5;
  int t = threadIdx.x, w = t >> 6, l = t & 63;
  int ln = l & 15, l4 = (l >> 4) * 4;
  __shared__ __align__(16) short lds[6144];  // A tile [128][32], B tile [64][32]
  f32x4 acc[2][4];
  #pragma unroll
  for (int m = 0; m < 2; ++m)
    #pragma unroll
    for (int n = 0; n < 4; ++n) { f32x4 z = {0.f, 0.f, 0.f, 0.f}; acc[m][n] = z; }

  int swd = ((l & 3) ^ ((l >> 2) & 3)) * 8;
  for (int kt = 0; kt < 16; ++kt) {
    if (kt) __syncthreads();
    #pragma unroll
    for (int i = 0; i < 3; ++i) {
      int s = i * 4 + w;               // 0..11; 0-7 A, 8-11 B
      int col = kt * 32 + swd;
      const bf16* g;
      if (s < 8) { int row = s * 16 + (l >> 2); g = gated + (size_t)(bm * 128 + row) * DIM + col; }
      else       { int r2 = (s - 8) * 16 + (l >> 2); g = wob + (size_t)(bn * 64 + r2) * DIM + col; }
      gld_lds16(g, lds + s * 512 + l * 8);
    }
    __syncthreads();
    int rc0 = (l >> 4);
    short8 a[2], b[4];
    #pragma unroll
    for (int m = 0; m < 2; ++m) {
      int row = w * 32 + m * 16 + ln;
      a[m] = *(const short8*)(lds + row * 32 + ((rc0 ^ (row & 3)) * 8));
    }
    #pragma unroll
    for (int n = 0; n < 4; ++n) {
      int row = n * 16 + ln;
      b[n] = *(const short8*)(lds + 4096 + row * 32 + ((rc0 ^ (row & 3)) * 8));
    }
    #pragma unroll
    for (int m = 0; m < 2; ++m)
      #pragma unroll
      for (int n = 0; n < 4; ++n)
        acc[m][n] = __builtin_amdgcn_mfma_f32_16x16x32_bf16(a[m], b[n], acc[m][n], 0, 0, 0);
  }

  #pragma unroll
  for (int m = 0; m < 2; ++m)
    #pragma unroll
    for (int n = 0; n < 4; ++n)
      #pragma unroll
      for (int j = 0; j < 4; ++j) {
        int rg = bm * 128 + w * 32 + m * 16 + l4 + j;
        int cg = bn * 64 + n * 16 + ln;
        size_t idx = (size_t)rg * DIM + cg;
        out[idx] = acc[m][n][j] + residual[idx];
      }
}

extern "C" void kernel_launch(void* const* d_in, const int* in_sizes, int n_in,
                              void* d_out, int out_size, void* d_ws, size_t ws_size,
                              hipStream_t stream) {
  const float* hidden    = (const float*)d_in[0];
  // d_in[1] = attention_mask (causal tril) — recomputed analytically
  const int*   ts        = (const int*)d_in[2];
  const float* ln_w      = (const float*)d_in[3];
  const float* attn_ln_w = (const float*)d_in[4];
  const float* wq        = (const float*)d_in[5];
  const float* wk        = (const float*)d_in[6];
  const float* wv        = (const float*)d_in[7];
  const float* wu        = (const float*)d_in[8];
  const float* wo        = (const float*)d_in[9];
  const float* ts_w      = (const float*)d_in[10];
  const float* pos_w     = (const float*)d_in[11];

  // OUTPUTS ARE FLOAT32: out [4,1024,512] then attn [4,8,1024,1024]
  float* out  = (float*)d_out;
  float* attn = out + 2097152;

  // workspace (~48 MiB < proven 58.7 MiB)
  bf16* wb    = (bf16*)d_ws;           // 5 * 512*512
  bf16* hb    = wb + 5 * DIM * DIM;    // [4096,512]
  bf16* q     = hb + 2097152;          // [b,h,l,d]
  bf16* k     = q + 2097152;
  bf16* v     = k + 2097152;           // [b,h,l,d]
  bf16* vT    = v + 2097152;           // [b,h,d,l]
  bf16* u     = vT + 2097152;          // [4096,512]
  bf16* gated = u + 2097152;           // [4096,512]
  float* ao0  = (float*)(gated + 2097152);  // [4096,512] f32
  float* ao1  = ao0 + 2097152;              // [4096,512] f32

  prep_k<<<2304, 256, 0, stream>>>(wq, wk, wv, wu, wo, wb, hidden, ln_w, hb);
  gemm_qkvu_k<<<dim3(128, 4), 256, 0, stream>>>(hb, wb, q, k, v, u);
  transpose_v_k<<<dim3(16, 32), 256, 0, stream>>>(v, vT);
  qk_attn_k<<<dim3(36, 32), 256, 0, stream>>>(q, k, ts, ts_w, pos_w, attn);
  pv_k<<<dim3(8, 32, 2), 256, 0, stream>>>(attn, vT, ao0, ao1);
  gated_k<<<4096, 64, 0, stream>>>(ao0, ao1, u, attn_ln_w, gated);
  gemm_out_k<<<256, 256, 0, stream>>>(gated, wb + 4 * DIM * DIM, hidden, out);
}

// Round 11
// 115.244 us; speedup vs baseline: 1.3163x; 1.0024x over previous
//
#include <hip/hip_runtime.h>
#include <hip/hip_bf16.h>

typedef __hip_bfloat16 bf16;
typedef __attribute__((ext_vector_type(8))) short short8;
typedef __attribute__((ext_vector_type(4))) float f32x4;

#define SL 1024
#define DIM 512
#define NH 8
#define HD 64
#define NBUCK 128

__device__ __forceinline__ float silu_f(float x) { return x / (1.0f + __expf(-x)); }

__device__ __forceinline__ short f2bf(float x) {
  bf16 b = __float2bfloat16(x);
  return *reinterpret_cast<short*>(&b);
}

__device__ __forceinline__ void gld_lds16(const void* g, void* l) {
  __builtin_amdgcn_global_load_lds(
      (const __attribute__((address_space(1))) void*)g,
      (__attribute__((address_space(3))) void*)l, 16, 0, 0);
}

// ---------- fused prep: weights f32->bf16 (blocks 0..1279) + rmsnorm (blocks 1280..2303) ----------
__global__ __launch_bounds__(256) void prep_k(const float* __restrict__ s0, const float* __restrict__ s1,
                                              const float* __restrict__ s2, const float* __restrict__ s3,
                                              const float* __restrict__ s4, bf16* __restrict__ wdst,
                                              const float* __restrict__ hidden, const float* __restrict__ ln_w,
                                              bf16* __restrict__ hb) {
  int bx = blockIdx.x;
  if (bx < 1280) {
    int wsel = bx >> 8;
    const float* src = wsel == 0 ? s0 : wsel == 1 ? s1 : wsel == 2 ? s2 : wsel == 3 ? s3 : s4;
    int i = ((bx & 255) * 256 + threadIdx.x) * 4;
    float4 v = *(const float4*)(src + i);
    bf16* d = wdst + (size_t)wsel * DIM * DIM + i;
    d[0] = __float2bfloat16(v.x);
    d[1] = __float2bfloat16(v.y);
    d[2] = __float2bfloat16(v.z);
    d[3] = __float2bfloat16(v.w);
  } else {
    int row = (bx - 1280) * 4 + (threadIdx.x >> 6);  // one row per wave
    int l = threadIdx.x & 63;
    const float4* xr = (const float4*)(hidden + (size_t)row * DIM);
    float4 v0 = xr[l], v1 = xr[l + 64];
    float s = v0.x*v0.x + v0.y*v0.y + v0.z*v0.z + v0.w*v0.w
            + v1.x*v1.x + v1.y*v1.y + v1.z*v1.z + v1.w*v1.w;
    #pragma unroll
    for (int o = 32; o; o >>= 1) s += __shfl_xor(s, o);
    float sc = rsqrtf(s * (1.0f / DIM) + 1e-6f);
    bf16* orow = hb + (size_t)row * DIM;
    int c0 = l * 4, c1 = 256 + l * 4;
    orow[c0 + 0] = __float2bfloat16(v0.x * sc * ln_w[c0 + 0]);
    orow[c0 + 1] = __float2bfloat16(v0.y * sc * ln_w[c0 + 1]);
    orow[c0 + 2] = __float2bfloat16(v0.z * sc * ln_w[c0 + 2]);
    orow[c0 + 3] = __float2bfloat16(v0.w * sc * ln_w[c0 + 3]);
    orow[c1 + 0] = __float2bfloat16(v1.x * sc * ln_w[c1 + 0]);
    orow[c1 + 1] = __float2bfloat16(v1.y * sc * ln_w[c1 + 1]);
    orow[c1 + 2] = __float2bfloat16(v1.z * sc * ln_w[c1 + 2]);
    orow[c1 + 3] = __float2bfloat16(v1.w * sc * ln_w[c1 + 3]);
  }
}

// ---------- shared 128x128 GEMM core, swizzled LDS (4-chunk rows: c ^= row&3) ----------
__device__ __forceinline__ void gemm128_core(const bf16* __restrict__ A,
                                             const bf16* __restrict__ Bt,
                                             short* lds, int bm, int bn,
                                             f32x4 acc[4][4]) {
  int t = threadIdx.x, w = t >> 6, l = t & 63;
  int ln = l & 15;
  int wr = (w >> 1) * 64, wc = (w & 1) * 64;
  int scol = ((l & 3) ^ ((l >> 2) & 3)) * 8;   // pre-swizzled source chunk
  for (int kt = 0; kt < 16; ++kt) {
    if (kt) __syncthreads();
    #pragma unroll
    for (int i = 0; i < 4; ++i) {
      int s = i * 4 + w;                 // 0..15; 0-7 = A tile, 8-15 = B tile
      int row = s * 16 + (l >> 2);       // within 0..255
      int col = kt * 32 + scol;
      const bf16* gsrc = (s < 8)
          ? (A  + (size_t)(bm * 128 + row) * DIM + col)
          : (Bt + (size_t)(bn * 128 + row - 128) * DIM + col);
      gld_lds16(gsrc, lds + s * 512 + l * 8);
    }
    __syncthreads();
    int rc = ((l >> 4) ^ (ln & 3)) * 8;        // swizzled read chunk
    short8 a[4], b[4];
    #pragma unroll
    for (int m = 0; m < 4; ++m)
      a[m] = *(const short8*)(lds + (wr + m * 16 + ln) * 32 + rc);
    #pragma unroll
    for (int n = 0; n < 4; ++n)
      b[n] = *(const short8*)(lds + 4096 + (wc + n * 16 + ln) * 32 + rc);
    #pragma unroll
    for (int m = 0; m < 4; ++m)
      #pragma unroll
      for (int n = 0; n < 4; ++n)
        acc[m][n] = __builtin_amdgcn_mfma_f32_16x16x32_bf16(a[m], b[n], acc[m][n], 0, 0, 0);
  }
}

// ---------- q,k,u = silu(h @ W^T) scattered; v-mode writes vT directly via LDS transpose ----------
// XCD swizzle: bm = x%32 so all bn-blocks of one bm land on one XCD (x%8 = bm%8)
__global__ __launch_bounds__(256) void gemm_qkvu_k(const bf16* __restrict__ hb,
                                                   const bf16* __restrict__ wb,
                                                   bf16* __restrict__ q, bf16* __restrict__ k,
                                                   bf16* __restrict__ vT, bf16* __restrict__ u) {
  __shared__ __align__(16) short lds[8320];   // 8192 for gemm; 128*65 for transpose
  int mode = blockIdx.y;
  int bm = blockIdx.x & 31, bn = blockIdx.x >> 5;
  f32x4 acc[4][4];
  #pragma unroll
  for (int m = 0; m < 4; ++m)
    #pragma unroll
    for (int n = 0; n < 4; ++n) { f32x4 z = {0.f, 0.f, 0.f, 0.f}; acc[m][n] = z; }
  gemm128_core(hb, wb + (size_t)mode * DIM * DIM, lds, bm, bn, acc);

  int t = threadIdx.x, w = t >> 6, l = t & 63;
  int ln = l & 15, l4 = (l >> 4) * 4;
  int wr = (w >> 1) * 64, wc = (w & 1) * 64;

  if (mode == 2) {
    // two half-tiles of 64 cols; each half = one head (hh = bn*2 + hc)
    int b = bm >> 3, li0 = (bm & 7) * 128;
    #pragma unroll
    for (int hc = 0; hc < 2; ++hc) {
      __syncthreads();                 // LDS free (gemm reads / previous half done)
      if ((w & 1) == hc) {             // warps whose wc == hc*64 own these cols
        #pragma unroll
        for (int m = 0; m < 4; ++m)
          #pragma unroll
          for (int n = 0; n < 4; ++n)
            #pragma unroll
            for (int j = 0; j < 4; ++j) {
              int rl = wr + m * 16 + l4 + j;   // 0..127
              int cl = n * 16 + ln;            // 0..63
              lds[rl * 65 + cl] = f2bf(silu_f(acc[m][n][j]));
            }
      }
      __syncthreads();
      int hh = bn * 2 + hc;
      int d = t >> 2, seg = t & 3;
      bf16* dst = vT + ((size_t)(b * NH + hh) * HD + d) * SL + li0 + seg * 32;
      short8 y0, y1, y2, y3;
      #pragma unroll
      for (int qq = 0; qq < 8; ++qq) {
        y0[qq] = lds[(seg * 32 + qq) * 65 + d];
        y1[qq] = lds[(seg * 32 + 8 + qq) * 65 + d];
        y2[qq] = lds[(seg * 32 + 16 + qq) * 65 + d];
        y3[qq] = lds[(seg * 32 + 24 + qq) * 65 + d];
      }
      *(short8*)dst = y0; *(short8*)(dst + 8) = y1;
      *(short8*)(dst + 16) = y2; *(short8*)(dst + 24) = y3;
    }
    return;
  }

  #pragma unroll
  for (int m = 0; m < 4; ++m)
    #pragma unroll
    for (int n = 0; n < 4; ++n)
      #pragma unroll
      for (int j = 0; j < 4; ++j) {
        int rg = bm * 128 + wr + m * 16 + l4 + j;
        int cg = bn * 128 + wc + n * 16 + ln;
        bf16 val = __float2bfloat16(silu_f(acc[m][n][j]));
        int b = rg >> 10, li = rg & 1023, hh = cg >> 6, dd = cg & 63;
        if (mode == 0)      q[((size_t)(b * NH + hh) * SL + li) * HD + dd] = val;
        else if (mode == 1) k[((size_t)(b * NH + hh) * SL + li) * HD + dd] = val;
        else                u[(size_t)rg * DIM + cg] = val;
      }
}

// ---------- attn = silu(q k^T + bias)/L, lower tiles + folded zero tiles ----------
__global__ __launch_bounds__(256) void qk_attn_k(const bf16* __restrict__ q,
                                                 const bf16* __restrict__ k,
                                                 const int* __restrict__ ts,
                                                 const float* __restrict__ ts_w,
                                                 const float* __restrict__ pos_w,
                                                 float* __restrict__ attn) {
  int bh = blockIdx.y, x = blockIdx.x;
  int ti = 0, accx = 0;
  while (accx + ti + 1 <= x) { accx += ti + 1; ++ti; }
  int tj = x - accx;                   // tj <= ti
  int t = threadIdx.x, w = t >> 6, l = t & 63;
  int ln = l & 15, l4 = (l >> 4) * 4;
  int wr = (w >> 1) * 64, wc = (w & 1) * 64;
  float* arow = attn + (size_t)bh * SL * SL;

  __shared__ __align__(16) short lds[16384];  // q tile [128][64], k tile [128][64]
  __shared__ float tw_l[NBUCK + 1];
  __shared__ float pw_l[255];
  __shared__ int tsi_l[128], tsj_l[128];

  const int* tsb = ts + (size_t)(bh >> 3) * SL;
  if (t < NBUCK + 1) tw_l[t] = ts_w[t];
  if (t < 255) pw_l[t] = pos_w[896 + (tj - ti) * 128 + t];
  if (t < 128) tsi_l[t] = tsb[min(ti * 128 + t + 1, SL - 1)];
  else         tsj_l[t - 128] = tsb[tj * 128 + (t - 128)];

  #pragma unroll
  for (int i = 0; i < 8; ++i) {
    int s = i * 4 + w;                 // 0..31; 0-15 q, 16-31 k
    int row = (s & 15) * 8 + (l >> 3);
    int col = ((l & 7) ^ (l >> 3)) * 8;   // pre-swizzled source (row&7 == l>>3)
    const bf16* g = (s < 16)
        ? (q + (size_t)bh * SL * HD + (size_t)(ti * 128 + row) * HD + col)
        : (k + (size_t)bh * SL * HD + (size_t)(tj * 128 + row) * HD + col);
    gld_lds16(g, lds + s * 512 + l * 8);
  }
  __syncthreads();

  f32x4 acc[4][4];
  #pragma unroll
  for (int m = 0; m < 4; ++m)
    #pragma unroll
    for (int n = 0; n < 4; ++n) { f32x4 z = {0.f, 0.f, 0.f, 0.f}; acc[m][n] = z; }
  #pragma unroll
  for (int kk = 0; kk < 2; ++kk) {        // chunk base 0 / 4
    short8 a[4], b[4];
    #pragma unroll
    for (int m = 0; m < 4; ++m) {
      int row = wr + m * 16 + ln;
      int c = ((kk * 4 + (l >> 4)) ^ (row & 7)) * 8;
      a[m] = *(const short8*)(lds + row * 64 + c);
    }
    #pragma unroll
    for (int n = 0; n < 4; ++n) {
      int row = wc + n * 16 + ln;
      int c = ((kk * 4 + (l >> 4)) ^ (row & 7)) * 8;
      b[n] = *(const short8*)(lds + 8192 + row * 64 + c);
    }
    #pragma unroll
    for (int m = 0; m < 4; ++m)
      #pragma unroll
      for (int n = 0; n < 4; ++n)
        acc[m][n] = __builtin_amdgcn_mfma_f32_16x16x32_bf16(a[m], b[n], acc[m][n], 0, 0, 0);
  }

  const float LSC = 2.30281455f;       // ln2 / 0.301
  #pragma unroll
  for (int m = 0; m < 4; ++m)
    #pragma unroll
    for (int j = 0; j < 4; ++j) {
      int il = wr + m * 16 + l4 + j;
      int tsi = tsi_l[il];
      int i = ti * 128 + il;
      #pragma unroll
      for (int n = 0; n < 4; ++n) {
        int jl = wc + n * 16 + ln;
        int jj = tj * 128 + jl;
        float v = acc[m][n][j];
        int dt = tsi - tsj_l[jl];
        float adf = fmaxf(fabsf((float)dt), 1.0f);
        int bucket = (int)(__log2f(adf) * LSC);
        bucket = bucket < 0 ? 0 : (bucket > NBUCK ? NBUCK : bucket);
        float bias = tw_l[bucket] + pw_l[jl - il + 127];
        float o = (jj <= i) ? silu_f(v + bias) * (1.0f / (float)SL) : 0.0f;
        arow[(size_t)i * SL + jj] = o;
      }
    }

  // folded zero-fill of one strict-upper tile (28 tiles over blocks 0..27)
  if (x < 28) {
    int zi = 0, acc2 = 0;
    while (acc2 + (7 - zi) <= x) { acc2 += 7 - zi; ++zi; }
    int zj = zi + 1 + (x - acc2);
    float4 z4 = make_float4(0.f, 0.f, 0.f, 0.f);
    #pragma unroll
    for (int rep = 0; rep < 16; ++rep) {
      int flat = rep * 256 + t;
      int row = flat >> 5, c4 = flat & 31;
      *(float4*)(arow + (size_t)(zi * 128 + row) * SL + zj * 128 + c4 * 4) = z4;
    }
  }
}

// ---------- partial attn_out (K-split=2); [_][32]-short tiles: c ^= row&3 ----------
__global__ __launch_bounds__(256) void pv_k(const float* __restrict__ attn,
                                            const bf16* __restrict__ vT,
                                            float* __restrict__ ao0,
                                            float* __restrict__ ao1) {
  int bh = blockIdx.y, bm = blockIdx.x, sp = blockIdx.z;
  int t = threadIdx.x, w = t >> 6, l = t & 63;
  int ln = l & 15, l4 = (l >> 4) * 4;
  __shared__ __align__(16) short lds[6144];  // A tile [128][32] bf16, B tile [64][32]
  const float* arow = attn + (size_t)bh * SL * SL;
  const bf16* vrow = vT + (size_t)bh * HD * SL;
  f32x4 acc[2][4];
  #pragma unroll
  for (int m = 0; m < 2; ++m)
    #pragma unroll
    for (int n = 0; n < 4; ++n) { f32x4 z = {0.f, 0.f, 0.f, 0.f}; acc[m][n] = z; }

  int swd = ((l & 3) ^ ((l >> 2) & 3)) * 8;  // swizzled dest/source chunk (row&3 == (l>>2)&3)
  int klo = sp * (bm + 1) * 2;         // half of ktmax=(bm+1)*4
  int khi = (sp + 1) * (bm + 1) * 2;
  for (int kt = klo; kt < khi; ++kt) {
    if (kt > klo) __syncthreads();
    // A tile: 8 slices from f32 attn, reg-converted to bf16, swizzled ds_write
    {
      int s = w * 2;                   // wave w covers slices {2w, 2w+1}
      #pragma unroll
      for (int ss = 0; ss < 2; ++ss, ++s) {
        int row = s * 16 + (l >> 2);
        int col = kt * 32 + (l & 3) * 8;
        const float* g = arow + (size_t)(bm * 128 + row) * SL + col;
        float4 f0 = *(const float4*)g;
        float4 f1 = *(const float4*)(g + 4);
        short8 vv;
        vv[0] = f2bf(f0.x); vv[1] = f2bf(f0.y); vv[2] = f2bf(f0.z); vv[3] = f2bf(f0.w);
        vv[4] = f2bf(f1.x); vv[5] = f2bf(f1.y); vv[6] = f2bf(f1.z); vv[7] = f2bf(f1.w);
        *(short8*)(lds + row * 32 + swd) = vv;
      }
    }
    // B tile: 4 slices from bf16 vT via async LDS, pre-swizzled source
    {
      int s = 8 + w;
      int r2 = (s - 8) * 16 + (l >> 2);
      int col = kt * 32 + swd;
      gld_lds16(vrow + (size_t)r2 * SL + col, lds + s * 512 + l * 8);
    }
    __syncthreads();
    int rc0 = (l >> 4);
    short8 a[2], b[4];
    #pragma unroll
    for (int m = 0; m < 2; ++m) {
      int row = w * 32 + m * 16 + ln;
      a[m] = *(const short8*)(lds + row * 32 + ((rc0 ^ (row & 3)) * 8));
    }
    #pragma unroll
    for (int n = 0; n < 4; ++n) {
      int row = n * 16 + ln;
      b[n] = *(const short8*)(lds + 4096 + row * 32 + ((rc0 ^ (row & 3)) * 8));
    }
    #pragma unroll
    for (int m = 0; m < 2; ++m)
      #pragma unroll
      for (int n = 0; n < 4; ++n)
        acc[m][n] = __builtin_amdgcn_mfma_f32_16x16x32_bf16(a[m], b[n], acc[m][n], 0, 0, 0);
  }

  float* aop = sp == 0 ? ao0 : ao1;
  int b = bh >> 3, hh = bh & 7;
  #pragma unroll
  for (int m = 0; m < 2; ++m)
    #pragma unroll
    for (int n = 0; n < 4; ++n)
      #pragma unroll
      for (int j = 0; j < 4; ++j) {
        int i = bm * 128 + w * 32 + m * 16 + l4 + j;
        int dd = n * 16 + ln;
        aop[((size_t)(b * SL + i)) * DIM + hh * HD + dd] = acc[m][n][j];
      }
}

// ---------- gated = u * rmsnorm(ao0+ao1) * attn_ln_w ----------
__global__ void gated_k(const float* __restrict__ ao0, const float* __restrict__ ao1,
                        const bf16* __restrict__ u,
                        const float* __restrict__ w, bf16* __restrict__ g) {
  int row = blockIdx.x, l = threadIdx.x;  // 64 threads
  const float4* ar0 = (const float4*)(ao0 + (size_t)row * DIM);
  const float4* ar1 = (const float4*)(ao1 + (size_t)row * DIM);
  float4 p0 = ar0[l], p1 = ar1[l], p2 = ar0[l + 64], p3 = ar1[l + 64];
  float4 a0 = make_float4(p0.x + p1.x, p0.y + p1.y, p0.z + p1.z, p0.w + p1.w);
  float4 a1 = make_float4(p2.x + p3.x, p2.y + p3.y, p2.z + p3.z, p2.w + p3.w);
  float s = a0.x*a0.x + a0.y*a0.y + a0.z*a0.z + a0.w*a0.w
          + a1.x*a1.x + a1.y*a1.y + a1.z*a1.z + a1.w*a1.w;
  #pragma unroll
  for (int o = 32; o; o >>= 1) s += __shfl_xor(s, o);
  float sc = rsqrtf(s * (1.0f / DIM) + 1e-6f);
  const bf16* ur = u + (size_t)row * DIM;
  bf16* gr = g + (size_t)row * DIM;
  int c0 = l * 4, c1 = 256 + l * 4;
  gr[c0 + 0] = __float2bfloat16(__bfloat162float(ur[c0 + 0]) * a0.x * sc * w[c0 + 0]);
  gr[c0 + 1] = __float2bfloat16(__bfloat162float(ur[c0 + 1]) * a0.y * sc * w[c0 + 1]);
  gr[c0 + 2] = __float2bfloat16(__bfloat162float(ur[c0 + 2]) * a0.z * sc * w[c0 + 2]);
  gr[c0 + 3] = __float2bfloat16(__bfloat162float(ur[c0 + 3]) * a0.w * sc * w[c0 + 3]);
  gr[c1 + 0] = __float2bfloat16(__bfloat162float(ur[c1 + 0]) * a1.x * sc * w[c1 + 0]);
  gr[c1 + 1] = __float2bfloat16(__bfloat162float(ur[c1 + 1]) * a1.y * sc * w[c1 + 1]);
  gr[c1 + 2] = __float2bfloat16(__bfloat162float(ur[c1 + 2]) * a1.z * sc * w[c1 + 2]);
  gr[c1 + 3] = __float2bfloat16(__bfloat162float(ur[c1 + 3]) * a1.w * sc * w[c1 + 3]);
}

// ---------- out = residual + gated @ wo^T, 128x64 tiles, XCD-swizzled ----------
__global__ __launch_bounds__(256) void gemm_out_k(const bf16* __restrict__ gated,
                                                  const bf16* __restrict__ wob,
                                                  const float* __restrict__ residual,
                                                  float* __restrict__ out) {
  int bm = blockIdx.x & 31, bn = blockIdx.x >> 5;
  int t = threadIdx.x, w = t >> 6, l = t & 63;
  int ln = l & 15, l4 = (l >> 4) * 4;
  __shared__ __align__(16) short lds[6144];  // A tile [128][32], B tile [64][32]
  f32x4 acc[2][4];
  #pragma unroll
  for (int m = 0; m < 2; ++m)
    #pragma unroll
    for (int n = 0; n < 4; ++n) { f32x4 z = {0.f, 0.f, 0.f, 0.f}; acc[m][n] = z; }

  int swd = ((l & 3) ^ ((l >> 2) & 3)) * 8;
  for (int kt = 0; kt < 16; ++kt) {
    if (kt) __syncthreads();
    #pragma unroll
    for (int i = 0; i < 3; ++i) {
      int s = i * 4 + w;               // 0..11; 0-7 A, 8-11 B
      int col = kt * 32 + swd;
      const bf16* g;
      if (s < 8) { int row = s * 16 + (l >> 2); g = gated + (size_t)(bm * 128 + row) * DIM + col; }
      else       { int r2 = (s - 8) * 16 + (l >> 2); g = wob + (size_t)(bn * 64 + r2) * DIM + col; }
      gld_lds16(g, lds + s * 512 + l * 8);
    }
    __syncthreads();
    int rc0 = (l >> 4);
    short8 a[2], b[4];
    #pragma unroll
    for (int m = 0; m < 2; ++m) {
      int row = w * 32 + m * 16 + ln;
      a[m] = *(const short8*)(lds + row * 32 + ((rc0 ^ (row & 3)) * 8));
    }
    #pragma unroll
    for (int n = 0; n < 4; ++n) {
      int row = n * 16 + ln;
      b[n] = *(const short8*)(lds + 4096 + row * 32 + ((rc0 ^ (row & 3)) * 8));
    }
    #pragma unroll
    for (int m = 0; m < 2; ++m)
      #pragma unroll
      for (int n = 0; n < 4; ++n)
        acc[m][n] = __builtin_amdgcn_mfma_f32_16x16x32_bf16(a[m], b[n], acc[m][n], 0, 0, 0);
  }

  #pragma unroll
  for (int m = 0; m < 2; ++m)
    #pragma unroll
    for (int n = 0; n < 4; ++n)
      #pragma unroll
      for (int j = 0; j < 4; ++j) {
        int rg = bm * 128 + w * 32 + m * 16 + l4 + j;
        int cg = bn * 64 + n * 16 + ln;
        size_t idx = (size_t)rg * DIM + cg;
        out[idx] = acc[m][n][j] + residual[idx];
      }
}

extern "C" void kernel_launch(void* const* d_in, const int* in_sizes, int n_in,
                              void* d_out, int out_size, void* d_ws, size_t ws_size,
                              hipStream_t stream) {
  const float* hidden    = (const float*)d_in[0];
  // d_in[1] = attention_mask (causal tril) — recomputed analytically
  const int*   ts        = (const int*)d_in[2];
  const float* ln_w      = (const float*)d_in[3];
  const float* attn_ln_w = (const float*)d_in[4];
  const float* wq        = (const float*)d_in[5];
  const float* wk        = (const float*)d_in[6];
  const float* wv        = (const float*)d_in[7];
  const float* wu        = (const float*)d_in[8];
  const float* wo        = (const float*)d_in[9];
  const float* ts_w      = (const float*)d_in[10];
  const float* pos_w     = (const float*)d_in[11];

  // OUTPUTS ARE FLOAT32: out [4,1024,512] then attn [4,8,1024,1024]
  float* out  = (float*)d_out;
  float* attn = out + 2097152;

  // workspace (~44.6 MiB < proven 56 MiB)
  bf16* wb    = (bf16*)d_ws;           // 5 * 512*512
  bf16* hb    = wb + 5 * DIM * DIM;    // [4096,512]
  bf16* q     = hb + 2097152;          // [b,h,l,d]
  bf16* k     = q + 2097152;
  bf16* vT    = k + 2097152;           // [b,h,d,l] (written directly by gemm_qkvu)
  bf16* u     = vT + 2097152;          // [4096,512]
  bf16* gated = u + 2097152;           // [4096,512]
  float* ao0  = (float*)(gated + 2097152);  // [4096,512] f32
  float* ao1  = ao0 + 2097152;              // [4096,512] f32

  prep_k<<<2304, 256, 0, stream>>>(wq, wk, wv, wu, wo, wb, hidden, ln_w, hb);
  gemm_qkvu_k<<<dim3(128, 4), 256, 0, stream>>>(hb, wb, q, k, vT, u);
  qk_attn_k<<<dim3(36, 32), 256, 0, stream>>>(q, k, ts, ts_w, pos_w, attn);
  pv_k<<<dim3(8, 32, 2), 256, 0, stream>>>(attn, vT, ao0, ao1);
  gated_k<<<4096, 64, 0, stream>>>(ao0, ao1, u, attn_ln_w, gated);
  gemm_out_k<<<256, 256, 0, stream>>>(gated, wb + 4 * DIM * DIM, hidden, out);
}

// Round 12
// 113.274 us; speedup vs baseline: 1.3392x; 1.0174x over previous
//
#include <hip/hip_runtime.h>
#include <hip/hip_bf16.h>

typedef __hip_bfloat16 bf16;
typedef __attribute__((ext_vector_type(8))) short short8;
typedef __attribute__((ext_vector_type(4))) float f32x4;

#define SL 1024
#define DIM 512
#define NH 8
#define HD 64
#define NBUCK 128

__device__ __forceinline__ float silu_f(float x) { return x / (1.0f + __expf(-x)); }

__device__ __forceinline__ short f2bf(float x) {
  bf16 b = __float2bfloat16(x);
  return *reinterpret_cast<short*>(&b);
}

__device__ __forceinline__ void gld_lds16(const void* g, void* l) {
  __builtin_amdgcn_global_load_lds(
      (const __attribute__((address_space(1))) void*)g,
      (__attribute__((address_space(3))) void*)l, 16, 0, 0);
}

// ---------- fused prep: weights f32->bf16 (blocks 0..1279) + rmsnorm (blocks 1280..2303) ----------
__global__ __launch_bounds__(256) void prep_k(const float* __restrict__ s0, const float* __restrict__ s1,
                                              const float* __restrict__ s2, const float* __restrict__ s3,
                                              const float* __restrict__ s4, bf16* __restrict__ wdst,
                                              const float* __restrict__ hidden, const float* __restrict__ ln_w,
                                              bf16* __restrict__ hb) {
  int bx = blockIdx.x;
  if (bx < 1280) {
    int wsel = bx >> 8;
    const float* src = wsel == 0 ? s0 : wsel == 1 ? s1 : wsel == 2 ? s2 : wsel == 3 ? s3 : s4;
    int i = ((bx & 255) * 256 + threadIdx.x) * 4;
    float4 v = *(const float4*)(src + i);
    bf16* d = wdst + (size_t)wsel * DIM * DIM + i;
    d[0] = __float2bfloat16(v.x);
    d[1] = __float2bfloat16(v.y);
    d[2] = __float2bfloat16(v.z);
    d[3] = __float2bfloat16(v.w);
  } else {
    int row = (bx - 1280) * 4 + (threadIdx.x >> 6);  // one row per wave
    int l = threadIdx.x & 63;
    const float4* xr = (const float4*)(hidden + (size_t)row * DIM);
    float4 v0 = xr[l], v1 = xr[l + 64];
    float s = v0.x*v0.x + v0.y*v0.y + v0.z*v0.z + v0.w*v0.w
            + v1.x*v1.x + v1.y*v1.y + v1.z*v1.z + v1.w*v1.w;
    #pragma unroll
    for (int o = 32; o; o >>= 1) s += __shfl_xor(s, o);
    float sc = rsqrtf(s * (1.0f / DIM) + 1e-6f);
    bf16* orow = hb + (size_t)row * DIM;
    int c0 = l * 4, c1 = 256 + l * 4;
    orow[c0 + 0] = __float2bfloat16(v0.x * sc * ln_w[c0 + 0]);
    orow[c0 + 1] = __float2bfloat16(v0.y * sc * ln_w[c0 + 1]);
    orow[c0 + 2] = __float2bfloat16(v0.z * sc * ln_w[c0 + 2]);
    orow[c0 + 3] = __float2bfloat16(v0.w * sc * ln_w[c0 + 3]);
    orow[c1 + 0] = __float2bfloat16(v1.x * sc * ln_w[c1 + 0]);
    orow[c1 + 1] = __float2bfloat16(v1.y * sc * ln_w[c1 + 1]);
    orow[c1 + 2] = __float2bfloat16(v1.z * sc * ln_w[c1 + 2]);
    orow[c1 + 3] = __float2bfloat16(v1.w * sc * ln_w[c1 + 3]);
  }
}

// ---------- 128x128 GEMM core, BK=64 (8 stages), qk_attn-style [128][64] swizzled tiles ----------
__device__ __forceinline__ void gemm128_core64(const bf16* __restrict__ A,
                                               const bf16* __restrict__ Bt,
                                               short* lds, int bm, int bn,
                                               f32x4 acc[4][4]) {
  int t = threadIdx.x, w = t >> 6, l = t & 63;
  int ln = l & 15;
  int wr = (w >> 1) * 64, wc = (w & 1) * 64;
  int srow8 = l >> 3;                       // row within 8-row slice
  int scol = ((l & 7) ^ srow8) * 8;         // pre-swizzled source chunk
  for (int kt = 0; kt < 8; ++kt) {
    if (kt) __syncthreads();
    #pragma unroll
    for (int i = 0; i < 8; ++i) {
      int s = i * 4 + w;                    // 0..31; 0-15 A, 16-31 B
      int row = (s & 15) * 8 + srow8;       // 0..127
      int col = kt * 64 + scol;
      const bf16* gsrc = (s < 16)
          ? (A  + (size_t)(bm * 128 + row) * DIM + col)
          : (Bt + (size_t)(bn * 128 + row) * DIM + col);
      gld_lds16(gsrc, lds + s * 512 + l * 8);
    }
    __syncthreads();
    #pragma unroll
    for (int kk = 0; kk < 2; ++kk) {
      short8 a[4], b[4];
      #pragma unroll
      for (int m = 0; m < 4; ++m) {
        int row = wr + m * 16 + ln;
        int c = ((kk * 4 + (l >> 4)) ^ (row & 7)) * 8;
        a[m] = *(const short8*)(lds + row * 64 + c);
      }
      #pragma unroll
      for (int n = 0; n < 4; ++n) {
        int row = wc + n * 16 + ln;
        int c = ((kk * 4 + (l >> 4)) ^ (row & 7)) * 8;
        b[n] = *(const short8*)(lds + 8192 + row * 64 + c);
      }
      #pragma unroll
      for (int m = 0; m < 4; ++m)
        #pragma unroll
        for (int n = 0; n < 4; ++n)
          acc[m][n] = __builtin_amdgcn_mfma_f32_16x16x32_bf16(a[m], b[n], acc[m][n], 0, 0, 0);
    }
  }
}

// ---------- q,k,u = silu(h @ W^T) scattered; v-mode writes vT directly via LDS transpose ----------
// XCD swizzle: bm = x%32 so all bn-blocks of one bm land on one XCD (x%8 = bm%8)
__global__ __launch_bounds__(256) void gemm_qkvu_k(const bf16* __restrict__ hb,
                                                   const bf16* __restrict__ wb,
                                                   bf16* __restrict__ q, bf16* __restrict__ k,
                                                   bf16* __restrict__ vT, bf16* __restrict__ u) {
  __shared__ __align__(16) short lds[16384];  // 32 KB gemm tiles; reused 128*65 for transpose
  int mode = blockIdx.y;
  int bm = blockIdx.x & 31, bn = blockIdx.x >> 5;
  f32x4 acc[4][4];
  #pragma unroll
  for (int m = 0; m < 4; ++m)
    #pragma unroll
    for (int n = 0; n < 4; ++n) { f32x4 z = {0.f, 0.f, 0.f, 0.f}; acc[m][n] = z; }
  gemm128_core64(hb, wb + (size_t)mode * DIM * DIM, lds, bm, bn, acc);

  int t = threadIdx.x, w = t >> 6, l = t & 63;
  int ln = l & 15, l4 = (l >> 4) * 4;
  int wr = (w >> 1) * 64, wc = (w & 1) * 64;

  if (mode == 2) {
    // two half-tiles of 64 cols; each half = one head (hh = bn*2 + hc)
    int b = bm >> 3, li0 = (bm & 7) * 128;
    #pragma unroll
    for (int hc = 0; hc < 2; ++hc) {
      __syncthreads();                 // LDS free (gemm reads / previous half done)
      if ((w & 1) == hc) {             // warps whose wc == hc*64 own these cols
        #pragma unroll
        for (int m = 0; m < 4; ++m)
          #pragma unroll
          for (int n = 0; n < 4; ++n)
            #pragma unroll
            for (int j = 0; j < 4; ++j) {
              int rl = wr + m * 16 + l4 + j;   // 0..127
              int cl = n * 16 + ln;            // 0..63
              lds[rl * 65 + cl] = f2bf(silu_f(acc[m][n][j]));
            }
      }
      __syncthreads();
      int hh = bn * 2 + hc;
      int d = t >> 2, seg = t & 3;
      bf16* dst = vT + ((size_t)(b * NH + hh) * HD + d) * SL + li0 + seg * 32;
      short8 y0, y1, y2, y3;
      #pragma unroll
      for (int qq = 0; qq < 8; ++qq) {
        y0[qq] = lds[(seg * 32 + qq) * 65 + d];
        y1[qq] = lds[(seg * 32 + 8 + qq) * 65 + d];
        y2[qq] = lds[(seg * 32 + 16 + qq) * 65 + d];
        y3[qq] = lds[(seg * 32 + 24 + qq) * 65 + d];
      }
      *(short8*)dst = y0; *(short8*)(dst + 8) = y1;
      *(short8*)(dst + 16) = y2; *(short8*)(dst + 24) = y3;
    }
    return;
  }

  #pragma unroll
  for (int m = 0; m < 4; ++m)
    #pragma unroll
    for (int n = 0; n < 4; ++n)
      #pragma unroll
      for (int j = 0; j < 4; ++j) {
        int rg = bm * 128 + wr + m * 16 + l4 + j;
        int cg = bn * 128 + wc + n * 16 + ln;
        bf16 val = __float2bfloat16(silu_f(acc[m][n][j]));
        int b = rg >> 10, li = rg & 1023, hh = cg >> 6, dd = cg & 63;
        if (mode == 0)      q[((size_t)(b * NH + hh) * SL + li) * HD + dd] = val;
        else if (mode == 1) k[((size_t)(b * NH + hh) * SL + li) * HD + dd] = val;
        else                u[(size_t)rg * DIM + cg] = val;
      }
}

// ---------- attn = silu(q k^T + bias)/L, lower tiles + folded zero tiles ----------
__global__ __launch_bounds__(256) void qk_attn_k(const bf16* __restrict__ q,
                                                 const bf16* __restrict__ k,
                                                 const int* __restrict__ ts,
                                                 const float* __restrict__ ts_w,
                                                 const float* __restrict__ pos_w,
                                                 float* __restrict__ attn) {
  int bh = blockIdx.y, x = blockIdx.x;
  int ti = 0, accx = 0;
  while (accx + ti + 1 <= x) { accx += ti + 1; ++ti; }
  int tj = x - accx;                   // tj <= ti
  int t = threadIdx.x, w = t >> 6, l = t & 63;
  int ln = l & 15, l4 = (l >> 4) * 4;
  int wr = (w >> 1) * 64, wc = (w & 1) * 64;
  float* arow = attn + (size_t)bh * SL * SL;

  __shared__ __align__(16) short lds[16384];  // q tile [128][64], k tile [128][64]
  __shared__ float tw_l[NBUCK + 1];
  __shared__ float pw_l[255];
  __shared__ int tsi_l[128], tsj_l[128];

  const int* tsb = ts + (size_t)(bh >> 3) * SL;
  if (t < NBUCK + 1) tw_l[t] = ts_w[t];
  if (t < 255) pw_l[t] = pos_w[896 + (tj - ti) * 128 + t];
  if (t < 128) tsi_l[t] = tsb[min(ti * 128 + t + 1, SL - 1)];
  else         tsj_l[t - 128] = tsb[tj * 128 + (t - 128)];

  #pragma unroll
  for (int i = 0; i < 8; ++i) {
    int s = i * 4 + w;                 // 0..31; 0-15 q, 16-31 k
    int row = (s & 15) * 8 + (l >> 3);
    int col = ((l & 7) ^ (l >> 3)) * 8;   // pre-swizzled source (row&7 == l>>3)
    const bf16* g = (s < 16)
        ? (q + (size_t)bh * SL * HD + (size_t)(ti * 128 + row) * HD + col)
        : (k + (size_t)bh * SL * HD + (size_t)(tj * 128 + row) * HD + col);
    gld_lds16(g, lds + s * 512 + l * 8);
  }
  __syncthreads();

  f32x4 acc[4][4];
  #pragma unroll
  for (int m = 0; m < 4; ++m)
    #pragma unroll
    for (int n = 0; n < 4; ++n) { f32x4 z = {0.f, 0.f, 0.f, 0.f}; acc[m][n] = z; }
  #pragma unroll
  for (int kk = 0; kk < 2; ++kk) {        // chunk base 0 / 4
    short8 a[4], b[4];
    #pragma unroll
    for (int m = 0; m < 4; ++m) {
      int row = wr + m * 16 + ln;
      int c = ((kk * 4 + (l >> 4)) ^ (row & 7)) * 8;
      a[m] = *(const short8*)(lds + row * 64 + c);
    }
    #pragma unroll
    for (int n = 0; n < 4; ++n) {
      int row = wc + n * 16 + ln;
      int c = ((kk * 4 + (l >> 4)) ^ (row & 7)) * 8;
      b[n] = *(const short8*)(lds + 8192 + row * 64 + c);
    }
    #pragma unroll
    for (int m = 0; m < 4; ++m)
      #pragma unroll
      for (int n = 0; n < 4; ++n)
        acc[m][n] = __builtin_amdgcn_mfma_f32_16x16x32_bf16(a[m], b[n], acc[m][n], 0, 0, 0);
  }

  const float LSC = 2.30281455f;       // ln2 / 0.301
  #pragma unroll
  for (int m = 0; m < 4; ++m)
    #pragma unroll
    for (int j = 0; j < 4; ++j) {
      int il = wr + m * 16 + l4 + j;
      int tsi = tsi_l[il];
      int i = ti * 128 + il;
      #pragma unroll
      for (int n = 0; n < 4; ++n) {
        int jl = wc + n * 16 + ln;
        int jj = tj * 128 + jl;
        float v = acc[m][n][j];
        int dt = tsi - tsj_l[jl];
        float adf = fmaxf(fabsf((float)dt), 1.0f);
        int bucket = (int)(__log2f(adf) * LSC);
        bucket = bucket < 0 ? 0 : (bucket > NBUCK ? NBUCK : bucket);
        float bias = tw_l[bucket] + pw_l[jl - il + 127];
        float o = (jj <= i) ? silu_f(v + bias) * (1.0f / (float)SL) : 0.0f;
        arow[(size_t)i * SL + jj] = o;
      }
    }

  // folded zero-fill of one strict-upper tile (28 tiles over blocks 0..27)
  if (x < 28) {
    int zi = 0, acc2 = 0;
    while (acc2 + (7 - zi) <= x) { acc2 += 7 - zi; ++zi; }
    int zj = zi + 1 + (x - acc2);
    float4 z4 = make_float4(0.f, 0.f, 0.f, 0.f);
    #pragma unroll
    for (int rep = 0; rep < 16; ++rep) {
      int flat = rep * 256 + t;
      int row = flat >> 5, c4 = flat & 31;
      *(float4*)(arow + (size_t)(zi * 128 + row) * SL + zj * 128 + c4 * 4) = z4;
    }
  }
}

// ---------- partial attn_out (K-split=2), BK=64: A [128][64] reg-staged, B(vT) [64][64] ----------
__global__ __launch_bounds__(256) void pv_k(const float* __restrict__ attn,
                                            const bf16* __restrict__ vT,
                                            float* __restrict__ ao0,
                                            float* __restrict__ ao1) {
  int bh = blockIdx.y, bm = blockIdx.x, sp = blockIdx.z;
  int t = threadIdx.x, w = t >> 6, l = t & 63;
  int ln = l & 15, l4 = (l >> 4) * 4;
  __shared__ __align__(16) short lds[12288];  // A [128][64] + B [64][64]
  const float* arow = attn + (size_t)bh * SL * SL;
  const bf16* vrow = vT + (size_t)bh * HD * SL;
  f32x4 acc[2][4];
  #pragma unroll
  for (int m = 0; m < 2; ++m)
    #pragma unroll
    for (int n = 0; n < 4; ++n) { f32x4 z = {0.f, 0.f, 0.f, 0.f}; acc[m][n] = z; }

  int srow8 = l >> 3;
  int swc = ((l & 7) ^ srow8) * 8;          // swizzled chunk (row&7 == l>>3)
  int klo = sp * (bm + 1);                  // (bm+1)*2 total 64-wide k-tiles, split in 2
  int khi = klo + (bm + 1);
  for (int kt = klo; kt < khi; ++kt) {
    if (kt > klo) __syncthreads();
    // A tile: 16 slices (4/wave) from f32 attn, reg-converted to bf16, swizzled ds_write
    #pragma unroll
    for (int ss = 0; ss < 4; ++ss) {
      int s = w * 4 + ss;                   // 0..15
      int row = s * 8 + srow8;              // 0..127
      const float* g = arow + (size_t)(bm * 128 + row) * SL + kt * 64 + (l & 7) * 8;
      float4 f0 = *(const float4*)g;
      float4 f1 = *(const float4*)(g + 4);
      short8 vv;
      vv[0] = f2bf(f0.x); vv[1] = f2bf(f0.y); vv[2] = f2bf(f0.z); vv[3] = f2bf(f0.w);
      vv[4] = f2bf(f1.x); vv[5] = f2bf(f1.y); vv[6] = f2bf(f1.z); vv[7] = f2bf(f1.w);
      *(short8*)(lds + row * 64 + swc) = vv;
    }
    // B tile: 8 slices (2/wave) from bf16 vT via async LDS, pre-swizzled source
    #pragma unroll
    for (int i = 0; i < 2; ++i) {
      int s2 = i * 4 + w;                   // 0..7
      int row = s2 * 8 + srow8;             // 0..63
      gld_lds16(vrow + (size_t)row * SL + kt * 64 + swc, lds + 8192 + s2 * 512 + l * 8);
    }
    __syncthreads();
    #pragma unroll
    for (int kk = 0; kk < 2; ++kk) {
      short8 a[2], b[4];
      #pragma unroll
      for (int m = 0; m < 2; ++m) {
        int row = w * 32 + m * 16 + ln;
        int c = ((kk * 4 + (l >> 4)) ^ (row & 7)) * 8;
        a[m] = *(const short8*)(lds + row * 64 + c);
      }
      #pragma unroll
      for (int n = 0; n < 4; ++n) {
        int row = n * 16 + ln;
        int c = ((kk * 4 + (l >> 4)) ^ (row & 7)) * 8;
        b[n] = *(const short8*)(lds + 8192 + row * 64 + c);
      }
      #pragma unroll
      for (int m = 0; m < 2; ++m)
        #pragma unroll
        for (int n = 0; n < 4; ++n)
          acc[m][n] = __builtin_amdgcn_mfma_f32_16x16x32_bf16(a[m], b[n], acc[m][n], 0, 0, 0);
    }
  }

  float* aop = sp == 0 ? ao0 : ao1;
  int b = bh >> 3, hh = bh & 7;
  #pragma unroll
  for (int m = 0; m < 2; ++m)
    #pragma unroll
    for (int n = 0; n < 4; ++n)
      #pragma unroll
      for (int j = 0; j < 4; ++j) {
        int i = bm * 128 + w * 32 + m * 16 + l4 + j;
        int dd = n * 16 + ln;
        aop[((size_t)(b * SL + i)) * DIM + hh * HD + dd] = acc[m][n][j];
      }
}

// ---------- gated = u * rmsnorm(ao0+ao1) * attn_ln_w ----------
__global__ void gated_k(const float* __restrict__ ao0, const float* __restrict__ ao1,
                        const bf16* __restrict__ u,
                        const float* __restrict__ w, bf16* __restrict__ g) {
  int row = blockIdx.x, l = threadIdx.x;  // 64 threads
  const float4* ar0 = (const float4*)(ao0 + (size_t)row * DIM);
  const float4* ar1 = (const float4*)(ao1 + (size_t)row * DIM);
  float4 p0 = ar0[l], p1 = ar1[l], p2 = ar0[l + 64], p3 = ar1[l + 64];
  float4 a0 = make_float4(p0.x + p1.x, p0.y + p1.y, p0.z + p1.z, p0.w + p1.w);
  float4 a1 = make_float4(p2.x + p3.x, p2.y + p3.y, p2.z + p3.z, p2.w + p3.w);
  float s = a0.x*a0.x + a0.y*a0.y + a0.z*a0.z + a0.w*a0.w
          + a1.x*a1.x + a1.y*a1.y + a1.z*a1.z + a1.w*a1.w;
  #pragma unroll
  for (int o = 32; o; o >>= 1) s += __shfl_xor(s, o);
  float sc = rsqrtf(s * (1.0f / DIM) + 1e-6f);
  const bf16* ur = u + (size_t)row * DIM;
  bf16* gr = g + (size_t)row * DIM;
  int c0 = l * 4, c1 = 256 + l * 4;
  gr[c0 + 0] = __float2bfloat16(__bfloat162float(ur[c0 + 0]) * a0.x * sc * w[c0 + 0]);
  gr[c0 + 1] = __float2bfloat16(__bfloat162float(ur[c0 + 1]) * a0.y * sc * w[c0 + 1]);
  gr[c0 + 2] = __float2bfloat16(__bfloat162float(ur[c0 + 2]) * a0.z * sc * w[c0 + 2]);
  gr[c0 + 3] = __float2bfloat16(__bfloat162float(ur[c0 + 3]) * a0.w * sc * w[c0 + 3]);
  gr[c1 + 0] = __float2bfloat16(__bfloat162float(ur[c1 + 0]) * a1.x * sc * w[c1 + 0]);
  gr[c1 + 1] = __float2bfloat16(__bfloat162float(ur[c1 + 1]) * a1.y * sc * w[c1 + 1]);
  gr[c1 + 2] = __float2bfloat16(__bfloat162float(ur[c1 + 2]) * a1.z * sc * w[c1 + 2]);
  gr[c1 + 3] = __float2bfloat16(__bfloat162float(ur[c1 + 3]) * a1.w * sc * w[c1 + 3]);
}

// ---------- out = residual + gated @ wo^T, 128x64 tiles, BK=64, XCD-swizzled ----------
__global__ __launch_bounds__(256) void gemm_out_k(const bf16* __restrict__ gated,
                                                  const bf16* __restrict__ wob,
                                                  const float* __restrict__ residual,
                                                  float* __restrict__ out) {
  int bm = blockIdx.x & 31, bn = blockIdx.x >> 5;
  int t = threadIdx.x, w = t >> 6, l = t & 63;
  int ln = l & 15, l4 = (l >> 4) * 4;
  __shared__ __align__(16) short lds[12288];  // A [128][64] + B [64][64]
  f32x4 acc[2][4];
  #pragma unroll
  for (int m = 0; m < 2; ++m)
    #pragma unroll
    for (int n = 0; n < 4; ++n) { f32x4 z = {0.f, 0.f, 0.f, 0.f}; acc[m][n] = z; }

  int srow8 = l >> 3;
  int scol = ((l & 7) ^ srow8) * 8;
  for (int kt = 0; kt < 8; ++kt) {
    if (kt) __syncthreads();
    #pragma unroll
    for (int i = 0; i < 6; ++i) {
      int s = i * 4 + w;                    // 0..23; 0-15 A (128 rows), 16-23 B (64 rows)
      int row = (s < 16 ? s : s - 16) * 8 + srow8;
      int col = kt * 64 + scol;
      const bf16* g = (s < 16)
          ? (gated + (size_t)(bm * 128 + row) * DIM + col)
          : (wob + (size_t)(bn * 64 + row) * DIM + col);
      gld_lds16(g, lds + s * 512 + l * 8);
    }
    __syncthreads();
    #pragma unroll
    for (int kk = 0; kk < 2; ++kk) {
      short8 a[2], b[4];
      #pragma unroll
      for (int m = 0; m < 2; ++m) {
        int row = w * 32 + m * 16 + ln;
        int c = ((kk * 4 + (l >> 4)) ^ (row & 7)) * 8;
        a[m] = *(const short8*)(lds + row * 64 + c);
      }
      #pragma unroll
      for (int n = 0; n < 4; ++n) {
        int row = n * 16 + ln;
        int c = ((kk * 4 + (l >> 4)) ^ (row & 7)) * 8;
        b[n] = *(const short8*)(lds + 8192 + row * 64 + c);
      }
      #pragma unroll
      for (int m = 0; m < 2; ++m)
        #pragma unroll
        for (int n = 0; n < 4; ++n)
          acc[m][n] = __builtin_amdgcn_mfma_f32_16x16x32_bf16(a[m], b[n], acc[m][n], 0, 0, 0);
    }
  }

  #pragma unroll
  for (int m = 0; m < 2; ++m)
    #pragma unroll
    for (int n = 0; n < 4; ++n)
      #pragma unroll
      for (int j = 0; j < 4; ++j) {
        int rg = bm * 128 + w * 32 + m * 16 + l4 + j;
        int cg = bn * 64 + n * 16 + ln;
        size_t idx = (size_t)rg * DIM + cg;
        out[idx] = acc[m][n][j] + residual[idx];
      }
}

extern "C" void kernel_launch(void* const* d_in, const int* in_sizes, int n_in,
                              void* d_out, int out_size, void* d_ws, size_t ws_size,
                              hipStream_t stream) {
  const float* hidden    = (const float*)d_in[0];
  // d_in[1] = attention_mask (causal tril) — recomputed analytically
  const int*   ts        = (const int*)d_in[2];
  const float* ln_w      = (const float*)d_in[3];
  const float* attn_ln_w = (const float*)d_in[4];
  const float* wq        = (const float*)d_in[5];
  const float* wk        = (const float*)d_in[6];
  const float* wv        = (const float*)d_in[7];
  const float* wu        = (const float*)d_in[8];
  const float* wo        = (const float*)d_in[9];
  const float* ts_w      = (const float*)d_in[10];
  const float* pos_w     = (const float*)d_in[11];

  // OUTPUTS ARE FLOAT32: out [4,1024,512] then attn [4,8,1024,1024]
  float* out  = (float*)d_out;
  float* attn = out + 2097152;

  // workspace (~44.6 MiB < proven 56 MiB)
  bf16* wb    = (bf16*)d_ws;           // 5 * 512*512
  bf16* hb    = wb + 5 * DIM * DIM;    // [4096,512]
  bf16* q     = hb + 2097152;          // [b,h,l,d]
  bf16* k     = q + 2097152;
  bf16* vT    = k + 2097152;           // [b,h,d,l] (written directly by gemm_qkvu)
  bf16* u     = vT + 2097152;          // [4096,512]
  bf16* gated = u + 2097152;           // [4096,512]
  float* ao0  = (float*)(gated + 2097152);  // [4096,512] f32
  float* ao1  = ao0 + 2097152;              // [4096,512] f32

  prep_k<<<2304, 256, 0, stream>>>(wq, wk, wv, wu, wo, wb, hidden, ln_w, hb);
  gemm_qkvu_k<<<dim3(128, 4), 256, 0, stream>>>(hb, wb, q, k, vT, u);
  qk_attn_k<<<dim3(36, 32), 256, 0, stream>>>(q, k, ts, ts_w, pos_w, attn);
  pv_k<<<dim3(8, 32, 2), 256, 0, stream>>>(attn, vT, ao0, ao1);
  gated_k<<<4096, 64, 0, stream>>>(ao0, ao1, u, attn_ln_w, gated);
  gemm_out_k<<<256, 256, 0, stream>>>(gated, wb + 4 * DIM * DIM, hidden, out);
}

// Round 13
// 103.266 us; speedup vs baseline: 1.4690x; 1.0969x over previous
//
#include <hip/hip_runtime.h>
#include <hip/hip_bf16.h>

typedef __hip_bfloat16 bf16;
typedef __attribute__((ext_vector_type(8))) short short8;
typedef __attribute__((ext_vector_type(4))) float f32x4;

#define SL 1024
#define DIM 512
#define NH 8
#define HD 64
#define NBUCK 128

__device__ __forceinline__ float silu_f(float x) { return x / (1.0f + __expf(-x)); }

__device__ __forceinline__ short f2bf(float x) {
  bf16 b = __float2bfloat16(x);
  return *reinterpret_cast<short*>(&b);
}

__device__ __forceinline__ void gld_lds16(const void* g, void* l) {
  __builtin_amdgcn_global_load_lds(
      (const __attribute__((address_space(1))) void*)g,
      (__attribute__((address_space(3))) void*)l, 16, 0, 0);
}

// ---------- fused prep: weights f32->bf16 (blocks 0..1279) + rmsnorm (blocks 1280..2303) ----------
__global__ __launch_bounds__(256) void prep_k(const float* __restrict__ s0, const float* __restrict__ s1,
                                              const float* __restrict__ s2, const float* __restrict__ s3,
                                              const float* __restrict__ s4, bf16* __restrict__ wdst,
                                              const float* __restrict__ hidden, const float* __restrict__ ln_w,
                                              bf16* __restrict__ hb) {
  int bx = blockIdx.x;
  if (bx < 1280) {
    int wsel = bx >> 8;
    const float* src = wsel == 0 ? s0 : wsel == 1 ? s1 : wsel == 2 ? s2 : wsel == 3 ? s3 : s4;
    int i = ((bx & 255) * 256 + threadIdx.x) * 4;
    float4 v = *(const float4*)(src + i);
    bf16* d = wdst + (size_t)wsel * DIM * DIM + i;
    d[0] = __float2bfloat16(v.x);
    d[1] = __float2bfloat16(v.y);
    d[2] = __float2bfloat16(v.z);
    d[3] = __float2bfloat16(v.w);
  } else {
    int row = (bx - 1280) * 4 + (threadIdx.x >> 6);  // one row per wave
    int l = threadIdx.x & 63;
    const float4* xr = (const float4*)(hidden + (size_t)row * DIM);
    float4 v0 = xr[l], v1 = xr[l + 64];
    float s = v0.x*v0.x + v0.y*v0.y + v0.z*v0.z + v0.w*v0.w
            + v1.x*v1.x + v1.y*v1.y + v1.z*v1.z + v1.w*v1.w;
    #pragma unroll
    for (int o = 32; o; o >>= 1) s += __shfl_xor(s, o);
    float sc = rsqrtf(s * (1.0f / DIM) + 1e-6f);
    bf16* orow = hb + (size_t)row * DIM;
    int c0 = l * 4, c1 = 256 + l * 4;
    orow[c0 + 0] = __float2bfloat16(v0.x * sc * ln_w[c0 + 0]);
    orow[c0 + 1] = __float2bfloat16(v0.y * sc * ln_w[c0 + 1]);
    orow[c0 + 2] = __float2bfloat16(v0.z * sc * ln_w[c0 + 2]);
    orow[c0 + 3] = __float2bfloat16(v0.w * sc * ln_w[c0 + 3]);
    orow[c1 + 0] = __float2bfloat16(v1.x * sc * ln_w[c1 + 0]);
    orow[c1 + 1] = __float2bfloat16(v1.y * sc * ln_w[c1 + 1]);
    orow[c1 + 2] = __float2bfloat16(v1.z * sc * ln_w[c1 + 2]);
    orow[c1 + 3] = __float2bfloat16(v1.w * sc * ln_w[c1 + 3]);
  }
}

// ---------- q,k,u,vT = silu(h @ W^T), 128x64 tiles (one head per tile), BK=64 ----------
// grid (256, 4): bm = x&31 (XCD swizzle), bn = x>>5 (head / 64-col panel), mode = y
__global__ __launch_bounds__(256) void gemm_qkvu_k(const bf16* __restrict__ hb,
                                                   const bf16* __restrict__ wb,
                                                   bf16* __restrict__ q, bf16* __restrict__ k,
                                                   bf16* __restrict__ vT, bf16* __restrict__ u) {
  int mode = blockIdx.y;
  int bm = blockIdx.x & 31, bn = blockIdx.x >> 5;
  int t = threadIdx.x, w = t >> 6, l = t & 63;
  int ln = l & 15, l4 = (l >> 4) * 4;
  __shared__ __align__(16) short lds[12288];  // A [128][64] + B [64][64]; reused 128*65 transpose
  const bf16* wbm = wb + (size_t)mode * DIM * DIM;
  f32x4 acc[2][4];
  #pragma unroll
  for (int m = 0; m < 2; ++m)
    #pragma unroll
    for (int n = 0; n < 4; ++n) { f32x4 z = {0.f, 0.f, 0.f, 0.f}; acc[m][n] = z; }

  int srow8 = l >> 3;
  int scol = ((l & 7) ^ srow8) * 8;
  for (int kt = 0; kt < 8; ++kt) {
    if (kt) __syncthreads();
    #pragma unroll
    for (int i = 0; i < 6; ++i) {
      int s = i * 4 + w;                    // 0..23; 0-15 A (128 rows), 16-23 B (64 rows)
      int row = (s < 16 ? s : s - 16) * 8 + srow8;
      int col = kt * 64 + scol;
      const bf16* g = (s < 16)
          ? (hb + (size_t)(bm * 128 + row) * DIM + col)
          : (wbm + (size_t)(bn * 64 + row) * DIM + col);
      gld_lds16(g, lds + s * 512 + l * 8);
    }
    __syncthreads();
    #pragma unroll
    for (int kk = 0; kk < 2; ++kk) {
      short8 a[2], b[4];
      #pragma unroll
      for (int m = 0; m < 2; ++m) {
        int row = w * 32 + m * 16 + ln;
        int c = ((kk * 4 + (l >> 4)) ^ (row & 7)) * 8;
        a[m] = *(const short8*)(lds + row * 64 + c);
      }
      #pragma unroll
      for (int n = 0; n < 4; ++n) {
        int row = n * 16 + ln;
        int c = ((kk * 4 + (l >> 4)) ^ (row & 7)) * 8;
        b[n] = *(const short8*)(lds + 8192 + row * 64 + c);
      }
      #pragma unroll
      for (int m = 0; m < 2; ++m)
        #pragma unroll
        for (int n = 0; n < 4; ++n)
          acc[m][n] = __builtin_amdgcn_mfma_f32_16x16x32_bf16(a[m], b[n], acc[m][n], 0, 0, 0);
    }
  }

  if (mode == 2) {
    // tile = one head's [128 rows]x[64 d]; transpose via LDS into vT[b,h,d,l]
    __syncthreads();                   // gemm reads done, LDS free
    #pragma unroll
    for (int m = 0; m < 2; ++m)
      #pragma unroll
      for (int n = 0; n < 4; ++n)
        #pragma unroll
        for (int j = 0; j < 4; ++j) {
          int rl = w * 32 + m * 16 + l4 + j;   // 0..127
          int cl = n * 16 + ln;                // 0..63
          lds[rl * 65 + cl] = f2bf(silu_f(acc[m][n][j]));
        }
    __syncthreads();
    int b = bm >> 3, li0 = (bm & 7) * 128;
    int d = t >> 2, seg = t & 3;
    bf16* dst = vT + ((size_t)(b * NH + bn) * HD + d) * SL + li0 + seg * 32;
    short8 y0, y1, y2, y3;
    #pragma unroll
    for (int qq = 0; qq < 8; ++qq) {
      y0[qq] = lds[(seg * 32 + qq) * 65 + d];
      y1[qq] = lds[(seg * 32 + 8 + qq) * 65 + d];
      y2[qq] = lds[(seg * 32 + 16 + qq) * 65 + d];
      y3[qq] = lds[(seg * 32 + 24 + qq) * 65 + d];
    }
    *(short8*)dst = y0; *(short8*)(dst + 8) = y1;
    *(short8*)(dst + 16) = y2; *(short8*)(dst + 24) = y3;
    return;
  }

  #pragma unroll
  for (int m = 0; m < 2; ++m)
    #pragma unroll
    for (int n = 0; n < 4; ++n)
      #pragma unroll
      for (int j = 0; j < 4; ++j) {
        int rg = bm * 128 + w * 32 + m * 16 + l4 + j;
        int c64 = n * 16 + ln;
        bf16 val = __float2bfloat16(silu_f(acc[m][n][j]));
        int b = rg >> 10, li = rg & 1023;
        if (mode == 0)      q[((size_t)(b * NH + bn) * SL + li) * HD + c64] = val;
        else if (mode == 1) k[((size_t)(b * NH + bn) * SL + li) * HD + c64] = val;
        else                u[(size_t)rg * DIM + bn * 64 + c64] = val;
      }
}

// ---------- attn = silu(q k^T + bias)/L, lower tiles + folded zero tiles ----------
__global__ __launch_bounds__(256) void qk_attn_k(const bf16* __restrict__ q,
                                                 const bf16* __restrict__ k,
                                                 const int* __restrict__ ts,
                                                 const float* __restrict__ ts_w,
                                                 const float* __restrict__ pos_w,
                                                 float* __restrict__ attn) {
  int bh = blockIdx.y, x = blockIdx.x;
  int ti = 0, accx = 0;
  while (accx + ti + 1 <= x) { accx += ti + 1; ++ti; }
  int tj = x - accx;                   // tj <= ti
  int t = threadIdx.x, w = t >> 6, l = t & 63;
  int ln = l & 15, l4 = (l >> 4) * 4;
  int wr = (w >> 1) * 64, wc = (w & 1) * 64;
  float* arow = attn + (size_t)bh * SL * SL;

  __shared__ __align__(16) short lds[16384];  // q tile [128][64], k tile [128][64]
  __shared__ float tw_l[NBUCK + 1];
  __shared__ float pw_l[255];
  __shared__ int tsi_l[128], tsj_l[128];

  const int* tsb = ts + (size_t)(bh >> 3) * SL;
  if (t < NBUCK + 1) tw_l[t] = ts_w[t];
  if (t < 255) pw_l[t] = pos_w[896 + (tj - ti) * 128 + t];
  if (t < 128) tsi_l[t] = tsb[min(ti * 128 + t + 1, SL - 1)];
  else         tsj_l[t - 128] = tsb[tj * 128 + (t - 128)];

  #pragma unroll
  for (int i = 0; i < 8; ++i) {
    int s = i * 4 + w;                 // 0..31; 0-15 q, 16-31 k
    int row = (s & 15) * 8 + (l >> 3);
    int col = ((l & 7) ^ (l >> 3)) * 8;   // pre-swizzled source (row&7 == l>>3)
    const bf16* g = (s < 16)
        ? (q + (size_t)bh * SL * HD + (size_t)(ti * 128 + row) * HD + col)
        : (k + (size_t)bh * SL * HD + (size_t)(tj * 128 + row) * HD + col);
    gld_lds16(g, lds + s * 512 + l * 8);
  }
  __syncthreads();

  f32x4 acc[4][4];
  #pragma unroll
  for (int m = 0; m < 4; ++m)
    #pragma unroll
    for (int n = 0; n < 4; ++n) { f32x4 z = {0.f, 0.f, 0.f, 0.f}; acc[m][n] = z; }
  #pragma unroll
  for (int kk = 0; kk < 2; ++kk) {        // chunk base 0 / 4
    short8 a[4], b[4];
    #pragma unroll
    for (int m = 0; m < 4; ++m) {
      int row = wr + m * 16 + ln;
      int c = ((kk * 4 + (l >> 4)) ^ (row & 7)) * 8;
      a[m] = *(const short8*)(lds + row * 64 + c);
    }
    #pragma unroll
    for (int n = 0; n < 4; ++n) {
      int row = wc + n * 16 + ln;
      int c = ((kk * 4 + (l >> 4)) ^ (row & 7)) * 8;
      b[n] = *(const short8*)(lds + 8192 + row * 64 + c);
    }
    #pragma unroll
    for (int m = 0; m < 4; ++m)
      #pragma unroll
      for (int n = 0; n < 4; ++n)
        acc[m][n] = __builtin_amdgcn_mfma_f32_16x16x32_bf16(a[m], b[n], acc[m][n], 0, 0, 0);
  }

  const float LSC = 2.30281455f;       // ln2 / 0.301
  #pragma unroll
  for (int m = 0; m < 4; ++m)
    #pragma unroll
    for (int j = 0; j < 4; ++j) {
      int il = wr + m * 16 + l4 + j;
      int tsi = tsi_l[il];
      int i = ti * 128 + il;
      #pragma unroll
      for (int n = 0; n < 4; ++n) {
        int jl = wc + n * 16 + ln;
        int jj = tj * 128 + jl;
        float v = acc[m][n][j];
        int dt = tsi - tsj_l[jl];
        float adf = fmaxf(fabsf((float)dt), 1.0f);
        int bucket = (int)(__log2f(adf) * LSC);
        bucket = bucket < 0 ? 0 : (bucket > NBUCK ? NBUCK : bucket);
        float bias = tw_l[bucket] + pw_l[jl - il + 127];
        float o = (jj <= i) ? silu_f(v + bias) * (1.0f / (float)SL) : 0.0f;
        arow[(size_t)i * SL + jj] = o;
      }
    }

  // folded zero-fill of one strict-upper tile (28 tiles over blocks 0..27)
  if (x < 28) {
    int zi = 0, acc2 = 0;
    while (acc2 + (7 - zi) <= x) { acc2 += 7 - zi; ++zi; }
    int zj = zi + 1 + (x - acc2);
    float4 z4 = make_float4(0.f, 0.f, 0.f, 0.f);
    #pragma unroll
    for (int rep = 0; rep < 16; ++rep) {
      int flat = rep * 256 + t;
      int row = flat >> 5, c4 = flat & 31;
      *(float4*)(arow + (size_t)(zi * 128 + row) * SL + zj * 128 + c4 * 4) = z4;
    }
  }
}

// ---------- partial attn_out, balanced chunks (<=6 kt64 units), 3 partial slots ----------
__global__ __launch_bounds__(256) void pv_k(const float* __restrict__ attn,
                                            const bf16* __restrict__ vT,
                                            float* __restrict__ ao0,
                                            float* __restrict__ ao1,
                                            float* __restrict__ ao2) {
  // chunk tables: per bm (0..7) the 2*(bm+1) kt64 units are split into <=3 chunks
  static const char cb_bm[17] = {0,1,2,2,3,3,4,4,5,5,5,6,6,6,7,7,7};
  static const char cb_lo[17] = {0,0,0,3,0,4,0,5,0,4,8,0,5,10,0,6,11};
  static const char cb_hi[17] = {2,4,3,6,4,8,5,10,4,8,12,5,10,14,6,11,16};
  static const char cb_sl[17] = {0,0,0,1,0,1,0,1,0,1,2,0,1,2,0,1,2};
  int ch = blockIdx.x, bh = blockIdx.y;
  int bm = cb_bm[ch], klo = cb_lo[ch], khi = cb_hi[ch], slot = cb_sl[ch];
  int t = threadIdx.x, w = t >> 6, l = t & 63;
  int ln = l & 15, l4 = (l >> 4) * 4;
  __shared__ __align__(16) short lds[12288];  // A [128][64] + B [64][64]
  const float* arow = attn + (size_t)bh * SL * SL;
  const bf16* vrow = vT + (size_t)bh * HD * SL;
  f32x4 acc[2][4];
  #pragma unroll
  for (int m = 0; m < 2; ++m)
    #pragma unroll
    for (int n = 0; n < 4; ++n) { f32x4 z = {0.f, 0.f, 0.f, 0.f}; acc[m][n] = z; }

  int srow8 = l >> 3;
  int swc = ((l & 7) ^ srow8) * 8;          // swizzled chunk (row&7 == l>>3)
  for (int kt = klo; kt < khi; ++kt) {
    if (kt > klo) __syncthreads();
    // A tile: 16 slices (4/wave) from f32 attn, reg-converted to bf16, swizzled ds_write
    #pragma unroll
    for (int ss = 0; ss < 4; ++ss) {
      int s = w * 4 + ss;                   // 0..15
      int row = s * 8 + srow8;              // 0..127
      const float* g = arow + (size_t)(bm * 128 + row) * SL + kt * 64 + (l & 7) * 8;
      float4 f0 = *(const float4*)g;
      float4 f1 = *(const float4*)(g + 4);
      short8 vv;
      vv[0] = f2bf(f0.x); vv[1] = f2bf(f0.y); vv[2] = f2bf(f0.z); vv[3] = f2bf(f0.w);
      vv[4] = f2bf(f1.x); vv[5] = f2bf(f1.y); vv[6] = f2bf(f1.z); vv[7] = f2bf(f1.w);
      *(short8*)(lds + row * 64 + swc) = vv;
    }
    // B tile: 8 slices (2/wave) from bf16 vT via async LDS, pre-swizzled source
    #pragma unroll
    for (int i = 0; i < 2; ++i) {
      int s2 = i * 4 + w;                   // 0..7
      int row = s2 * 8 + srow8;             // 0..63
      gld_lds16(vrow + (size_t)row * SL + kt * 64 + swc, lds + 8192 + s2 * 512 + l * 8);
    }
    __syncthreads();
    #pragma unroll
    for (int kk = 0; kk < 2; ++kk) {
      short8 a[2], b[4];
      #pragma unroll
      for (int m = 0; m < 2; ++m) {
        int row = w * 32 + m * 16 + ln;
        int c = ((kk * 4 + (l >> 4)) ^ (row & 7)) * 8;
        a[m] = *(const short8*)(lds + row * 64 + c);
      }
      #pragma unroll
      for (int n = 0; n < 4; ++n) {
        int row = n * 16 + ln;
        int c = ((kk * 4 + (l >> 4)) ^ (row & 7)) * 8;
        b[n] = *(const short8*)(lds + 8192 + row * 64 + c);
      }
      #pragma unroll
      for (int m = 0; m < 2; ++m)
        #pragma unroll
        for (int n = 0; n < 4; ++n)
          acc[m][n] = __builtin_amdgcn_mfma_f32_16x16x32_bf16(a[m], b[n], acc[m][n], 0, 0, 0);
    }
  }

  float* aop = slot == 0 ? ao0 : (slot == 1 ? ao1 : ao2);
  int b = bh >> 3, hh = bh & 7;
  #pragma unroll
  for (int m = 0; m < 2; ++m)
    #pragma unroll
    for (int n = 0; n < 4; ++n)
      #pragma unroll
      for (int j = 0; j < 4; ++j) {
        int i = bm * 128 + w * 32 + m * 16 + l4 + j;
        int dd = n * 16 + ln;
        aop[((size_t)(b * SL + i)) * DIM + hh * HD + dd] = acc[m][n][j];
      }
}

// ---------- gated = u * rmsnorm(sum of partials) * attn_ln_w ----------
// partial count per 128-row band: {1,1,2,2,2,3,3,3}
__global__ void gated_k(const float* __restrict__ ao0, const float* __restrict__ ao1,
                        const float* __restrict__ ao2, const bf16* __restrict__ u,
                        const float* __restrict__ w, bf16* __restrict__ g) {
  int row = blockIdx.x, l = threadIdx.x;  // 64 threads
  int bmRow = (row & 1023) >> 7;
  const float4* ar0 = (const float4*)(ao0 + (size_t)row * DIM);
  const float4* ar1 = (const float4*)(ao1 + (size_t)row * DIM);
  const float4* ar2 = (const float4*)(ao2 + (size_t)row * DIM);
  float4 a0 = ar0[l], a1 = ar0[l + 64];
  if (bmRow >= 2) {
    float4 p0 = ar1[l], p1 = ar1[l + 64];
    a0.x += p0.x; a0.y += p0.y; a0.z += p0.z; a0.w += p0.w;
    a1.x += p1.x; a1.y += p1.y; a1.z += p1.z; a1.w += p1.w;
  }
  if (bmRow >= 5) {
    float4 p0 = ar2[l], p1 = ar2[l + 64];
    a0.x += p0.x; a0.y += p0.y; a0.z += p0.z; a0.w += p0.w;
    a1.x += p1.x; a1.y += p1.y; a1.z += p1.z; a1.w += p1.w;
  }
  float s = a0.x*a0.x + a0.y*a0.y + a0.z*a0.z + a0.w*a0.w
          + a1.x*a1.x + a1.y*a1.y + a1.z*a1.z + a1.w*a1.w;
  #pragma unroll
  for (int o = 32; o; o >>= 1) s += __shfl_xor(s, o);
  float sc = rsqrtf(s * (1.0f / DIM) + 1e-6f);
  const bf16* ur = u + (size_t)row * DIM;
  bf16* gr = g + (size_t)row * DIM;
  int c0 = l * 4, c1 = 256 + l * 4;
  gr[c0 + 0] = __float2bfloat16(__bfloat162float(ur[c0 + 0]) * a0.x * sc * w[c0 + 0]);
  gr[c0 + 1] = __float2bfloat16(__bfloat162float(ur[c0 + 1]) * a0.y * sc * w[c0 + 1]);
  gr[c0 + 2] = __float2bfloat16(__bfloat162float(ur[c0 + 2]) * a0.z * sc * w[c0 + 2]);
  gr[c0 + 3] = __float2bfloat16(__bfloat162float(ur[c0 + 3]) * a0.w * sc * w[c0 + 3]);
  gr[c1 + 0] = __float2bfloat16(__bfloat162float(ur[c1 + 0]) * a1.x * sc * w[c1 + 0]);
  gr[c1 + 1] = __float2bfloat16(__bfloat162float(ur[c1 + 1]) * a1.y * sc * w[c1 + 1]);
  gr[c1 + 2] = __float2bfloat16(__bfloat162float(ur[c1 + 2]) * a1.z * sc * w[c1 + 2]);
  gr[c1 + 3] = __float2bfloat16(__bfloat162float(ur[c1 + 3]) * a1.w * sc * w[c1 + 3]);
}

// ---------- out = residual + gated @ wo^T, 128x64 tiles, BK=64, XCD-swizzled ----------
__global__ __launch_bounds__(256) void gemm_out_k(const bf16* __restrict__ gated,
                                                  const bf16* __restrict__ wob,
                                                  const float* __restrict__ residual,
                                                  float* __restrict__ out) {
  int bm = blockIdx.x & 31, bn = blockIdx.x >> 5;
  int t = threadIdx.x, w = t >> 6, l = t & 63;
  int ln = l & 15, l4 = (l >> 4) * 4;
  __shared__ __align__(16) short lds[12288];  // A [128][64] + B [64][64]
  f32x4 acc[2][4];
  #pragma unroll
  for (int m = 0; m < 2; ++m)
    #pragma unroll
    for (int n = 0; n < 4; ++n) { f32x4 z = {0.f, 0.f, 0.f, 0.f}; acc[m][n] = z; }

  int srow8 = l >> 3;
  int scol = ((l & 7) ^ srow8) * 8;
  for (int kt = 0; kt < 8; ++kt) {
    if (kt) __syncthreads();
    #pragma unroll
    for (int i = 0; i < 6; ++i) {
      int s = i * 4 + w;                    // 0..23; 0-15 A (128 rows), 16-23 B (64 rows)
      int row = (s < 16 ? s : s - 16) * 8 + srow8;
      int col = kt * 64 + scol;
      const bf16* g = (s < 16)
          ? (gated + (size_t)(bm * 128 + row) * DIM + col)
          : (wob + (size_t)(bn * 64 + row) * DIM + col);
      gld_lds16(g, lds + s * 512 + l * 8);
    }
    __syncthreads();
    #pragma unroll
    for (int kk = 0; kk < 2; ++kk) {
      short8 a[2], b[4];
      #pragma unroll
      for (int m = 0; m < 2; ++m) {
        int row = w * 32 + m * 16 + ln;
        int c = ((kk * 4 + (l >> 4)) ^ (row & 7)) * 8;
        a[m] = *(const short8*)(lds + row * 64 + c);
      }
      #pragma unroll
      for (int n = 0; n < 4; ++n) {
        int row = n * 16 + ln;
        int c = ((kk * 4 + (l >> 4)) ^ (row & 7)) * 8;
        b[n] = *(const short8*)(lds + 8192 + row * 64 + c);
      }
      #pragma unroll
      for (int m = 0; m < 2; ++m)
        #pragma unroll
        for (int n = 0; n < 4; ++n)
          acc[m][n] = __builtin_amdgcn_mfma_f32_16x16x32_bf16(a[m], b[n], acc[m][n], 0, 0, 0);
    }
  }

  #pragma unroll
  for (int m = 0; m < 2; ++m)
    #pragma unroll
    for (int n = 0; n < 4; ++n)
      #pragma unroll
      for (int j = 0; j < 4; ++j) {
        int rg = bm * 128 + w * 32 + m * 16 + l4 + j;
        int cg = bn * 64 + n * 16 + ln;
        size_t idx = (size_t)rg * DIM + cg;
        out[idx] = acc[m][n][j] + residual[idx];
      }
}

extern "C" void kernel_launch(void* const* d_in, const int* in_sizes, int n_in,
                              void* d_out, int out_size, void* d_ws, size_t ws_size,
                              hipStream_t stream) {
  const float* hidden    = (const float*)d_in[0];
  // d_in[1] = attention_mask (causal tril) — recomputed analytically
  const int*   ts        = (const int*)d_in[2];
  const float* ln_w      = (const float*)d_in[3];
  const float* attn_ln_w = (const float*)d_in[4];
  const float* wq        = (const float*)d_in[5];
  const float* wk        = (const float*)d_in[6];
  const float* wv        = (const float*)d_in[7];
  const float* wu        = (const float*)d_in[8];
  const float* wo        = (const float*)d_in[9];
  const float* ts_w      = (const float*)d_in[10];
  const float* pos_w     = (const float*)d_in[11];

  // OUTPUTS ARE FLOAT32: out [4,1024,512] then attn [4,8,1024,1024]
  float* out  = (float*)d_out;
  float* attn = out + 2097152;

  // workspace (~44.6 MiB < proven 56 MiB); ao2 overlays hb+q (dead by pv time)
  bf16* wb    = (bf16*)d_ws;           // 5 * 512*512
  bf16* hb    = wb + 5 * DIM * DIM;    // [4096,512]
  bf16* q     = hb + 2097152;          // [b,h,l,d]
  bf16* k     = q + 2097152;
  bf16* vT    = k + 2097152;           // [b,h,d,l] (written directly by gemm_qkvu)
  bf16* u     = vT + 2097152;          // [4096,512]
  bf16* gated = u + 2097152;           // [4096,512]
  float* ao0  = (float*)(gated + 2097152);  // [4096,512] f32
  float* ao1  = ao0 + 2097152;              // [4096,512] f32
  float* ao2  = (float*)hb;                 // overlay: hb(4MB)+q(4MB) dead after qk_attn

  prep_k<<<2304, 256, 0, stream>>>(wq, wk, wv, wu, wo, wb, hidden, ln_w, hb);
  gemm_qkvu_k<<<dim3(256, 4), 256, 0, stream>>>(hb, wb, q, k, vT, u);
  qk_attn_k<<<dim3(36, 32), 256, 0, stream>>>(q, k, ts, ts_w, pos_w, attn);
  pv_k<<<dim3(17, 32), 256, 0, stream>>>(attn, vT, ao0, ao1, ao2);
  gated_k<<<4096, 64, 0, stream>>>(ao0, ao1, ao2, u, attn_ln_w, gated);
  gemm_out_k<<<256, 256, 0, stream>>>(gated, wb + 4 * DIM * DIM, hidden, out);
}